// Round 7
// baseline (600.505 us; speedup 1.0000x reference)
//
#include <hip/hip_runtime.h>
#include <stdint.h>
#include <math.h>

static constexpr int B_   = 4;
static constexpr int N1   = 255780;   // total anchors per image across 5 levels
static constexpr int PRE  = 6000;
static constexpr int PREP = 6016;     // padded rows (multiple of 64) for tile DMA
static constexpr int POST = 1000;
static constexpr int MWORDS = 94;     // ceil(6000/64)
static constexpr int NCAND = 8192;    // candidate capacity per image
static constexpr int NPOSTS = 6144;   // padded post-slot count
static constexpr float NEGF = -1000000000.0f;

#define GLOBAL_AS __attribute__((address_space(1)))
#define LDS_AS    __attribute__((address_space(3)))

__device__ __constant__ int c_OFF[6] = {0,192000,240000,252000,255000,255780};
__device__ __constant__ int c_H[5]   = {200,100,50,25,13};
__device__ __constant__ int c_W[5]   = {320,160,80,40,20};
__device__ __constant__ int c_S[5]   = {4,8,16,32,64};

struct Ptrs { const float* cls[5]; const float* bbox[5]; };

// ---------- helpers ----------
__device__ __forceinline__ unsigned forder(float f) {
  unsigned u = __float_as_uint(f);
  return (u & 0x80000000u) ? ~u : (u | 0x80000000u);
}
__device__ __forceinline__ float funorder(unsigned u) {
  u = (u & 0x80000000u) ? (u & 0x7FFFFFFFu) : ~u;
  return __uint_as_float(u);
}
__device__ __forceinline__ int bucket_of(float s) {
  int bk = (int)(s * 4096.0f);
  return max(0, min(4095, bk));
}

// base anchor (legacy +1 convention), double math == numpy float64, rint == np.round
__device__ __forceinline__ void anchor_for(int lvl, int a, float& ax1, float& ay1, float& ax2, float& ay2) {
  int st = c_S[lvl];
  double size = (double)st * (double)st;
  double c = 0.5 * (double)(st - 1);
  double r = (a == 0) ? 0.5 : (a == 1) ? 1.0 : 2.0;
  double ws = rint(sqrt(size / r));
  double hs = rint(ws * r);
  double w2 = ws * 8.0, h2 = hs * 8.0;
  ax1 = (float)(c - 0.5 * (w2 - 1.0));
  ay1 = (float)(c - 0.5 * (h2 - 1.0));
  ax2 = (float)(c + 0.5 * (w2 - 1.0));
  ay2 = (float)(c + 0.5 * (h2 - 1.0));
}

// decode one anchor exactly as the reference (per-op f32 rounding, no FMA)
__device__ __forceinline__ void decode_one(const Ptrs& P, int b, int gi, float wlim, float hlim,
                                           float& x1, float& y1, float& x2, float& y2, bool& valid) {
  int lvl = (gi >= c_OFF[4]) ? 4 : (gi >= c_OFF[3]) ? 3 : (gi >= c_OFF[2]) ? 2 : (gi >= c_OFF[1]) ? 1 : 0;
  int rem = gi - c_OFF[lvl];
  int a = rem % 3;
  int pos = rem / 3;
  int W = c_W[lvl];
  int h = pos / W, w = pos - h * W;
  size_t hw = (size_t)c_H[lvl] * W;
  const float* bb = P.bbox[lvl] + ((size_t)b * 12 + 4 * a) * hw + (size_t)h * W + w;
  float d0 = bb[0], d1 = bb[hw], d2 = bb[2 * hw], d3 = bb[3 * hw];

  float ax1, ay1, ax2, ay2;
  anchor_for(lvl, a, ax1, ay1, ax2, ay2);
  int st = c_S[lvl];
  float sx = (float)(w * st), sy = (float)(h * st);
  ax1 += sx; ax2 += sx; ay1 += sy; ay2 += sy;   // exact integers

  float aw  = __fadd_rn(__fsub_rn(ax2, ax1), 1.0f);
  float ah  = __fadd_rn(__fsub_rn(ay2, ay1), 1.0f);
  float acx = __fadd_rn(ax1, __fmul_rn(0.5f, __fsub_rn(aw, 1.0f)));
  float acy = __fadd_rn(ay1, __fmul_rn(0.5f, __fsub_rn(ah, 1.0f)));
  float ew  = (float)exp((double)d2);
  float eh  = (float)exp((double)d3);
  float pcx = __fadd_rn(__fmul_rn(d0, aw), acx);
  float pcy = __fadd_rn(__fmul_rn(d1, ah), acy);
  float pw  = __fmul_rn(ew, aw);
  float ph  = __fmul_rn(eh, ah);
  float hwf = __fmul_rn(0.5f, __fsub_rn(pw, 1.0f));
  float hhf = __fmul_rn(0.5f, __fsub_rn(ph, 1.0f));
  x1 = __fsub_rn(pcx, hwf);
  x2 = __fadd_rn(pcx, hwf);
  y1 = __fsub_rn(pcy, hhf);
  y2 = __fadd_rn(pcy, hhf);
  x1 = fminf(fmaxf(x1, 0.0f), wlim);
  x2 = fminf(fmaxf(x2, 0.0f), wlim);
  y1 = fminf(fmaxf(y1, 0.0f), hlim);
  y2 = fminf(fmaxf(y2, 0.0f), hlim);
  valid = (__fadd_rn(__fsub_rn(x2, x1), 1.0f) >= 0.0f) &&
          (__fadd_rn(__fsub_rn(y2, y1), 1.0f) >= 0.0f);
}

// ---------- kernel 0: zero hist/cnt/cand/ranks + mask padding rows ----------
__global__ void k_init(int* hist, int* cnt, unsigned long long* cand,
                       int* rankA, int* rankB, int* rankC, unsigned long long* mask) {
  int i = blockIdx.x * blockDim.x + threadIdx.x;
  int n = blockDim.x * gridDim.x;
  for (int k = i; k < B_ * 4096; k += n) hist[k] = 0;
  for (int k = i; k < B_; k += n) cnt[k] = 0;
  for (int k = i; k < B_ * NCAND; k += n) cand[k] = 0ull;
  for (int k = i; k < B_ * NCAND; k += n) rankA[k] = 0;
  for (int k = i; k < B_ * NPOSTS; k += n) rankB[k] = 0;
  for (int k = i; k < 4096; k += n) rankC[k] = 0;
  // zero padding rows PRE..PREP-1 of each image
  int padw = (PREP - PRE) * MWORDS;          // 16*94
  for (int k = i; k < B_ * padw; k += n) {
    int bb = k / padw, r = k % padw;
    mask[((size_t)bb * PREP + PRE) * MWORDS + r] = 0ull;
  }
}

// ---------- kernel A: masked scores + global histogram ----------
__global__ void k_scores(Ptrs P, const float* im_info, float* scores, int* hist) {
  int i = blockIdx.x * blockDim.x + threadIdx.x;
  int b = blockIdx.y;
  if (i >= N1) return;
  float wlim = __fsub_rn(im_info[b * 3 + 1], 1.0f);
  float hlim = __fsub_rn(im_info[b * 3 + 0], 1.0f);
  float x1, y1, x2, y2; bool valid;
  decode_one(P, b, i, wlim, hlim, x1, y1, x2, y2, valid);

  int lvl = (i >= c_OFF[4]) ? 4 : (i >= c_OFF[3]) ? 3 : (i >= c_OFF[2]) ? 2 : (i >= c_OFF[1]) ? 1 : 0;
  int rem = i - c_OFF[lvl];
  int a = rem % 3;
  int pos = rem / 3;
  int W = c_W[lvl];
  int h = pos / W, w = pos - h * W;
  size_t hw = (size_t)c_H[lvl] * W;
  float s = P.cls[lvl][((size_t)b * 6 + 3 + a) * hw + (size_t)h * W + w];
  float sv = valid ? s : NEGF;
  scores[(size_t)b * N1 + i] = sv;
  atomicAdd(&hist[b * 4096 + bucket_of(sv)], 1);
}

// ---------- kernel B1: cutoff bin per image (parallel suffix-sum) ----------
__global__ __launch_bounds__(1024) void k_cut(const int* hist, int* cutM) {
  int b = blockIdx.x, t = threadIdx.x;
  __shared__ int h[4096];
  __shared__ int ts[1024];
  __shared__ int s_cut, s_M;
  for (int i = t; i < 4096; i += 1024) h[i] = hist[b * 4096 + i];
  if (t == 0) { s_cut = -1; s_M = 0; }
  __syncthreads();
  int a0 = h[4 * t], a1 = h[4 * t + 1], a2 = h[4 * t + 2], a3 = h[4 * t + 3];
  ts[t] = a0 + a1 + a2 + a3;
  __syncthreads();
  for (int off = 1; off < 1024; off <<= 1) {
    int v = ts[t] + ((t + off < 1024) ? ts[t + off] : 0);
    __syncthreads();
    ts[t] = v;
    __syncthreads();
  }
  int tail = (t + 1 < 1024) ? ts[t + 1] : 0;
  int s3 = a3 + tail, s2 = a2 + s3, s1 = a1 + s2, s0 = a0 + s1;
  int best = -1, Mv = 0;
  if      (s3 >= PRE) { best = 4 * t + 3; Mv = s3; }
  else if (s2 >= PRE) { best = 4 * t + 2; Mv = s2; }
  else if (s1 >= PRE) { best = 4 * t + 1; Mv = s1; }
  else if (s0 >= PRE) { best = 4 * t;     Mv = s0; }
  if (best >= 0) atomicMax(&s_cut, best);
  __syncthreads();
  if (s_cut == -1) { if (t == 0) { cutM[b * 2] = 0; cutM[b * 2 + 1] = ts[0]; } return; }
  if (best == s_cut) { cutM[b * 2] = best; cutM[b * 2 + 1] = Mv; }
}

// ---------- kernel B2: compact candidate keys (unordered) ----------
__global__ void k_compact(const float* scores, const int* cutM, int* cnt,
                          unsigned long long* cand) {
  int i = blockIdx.x * blockDim.x + threadIdx.x;
  int b = blockIdx.y;
  if (i >= N1) return;
  float s = scores[(size_t)b * N1 + i];
  if (bucket_of(s) >= cutM[b * 2]) {
    int p = atomicAdd(&cnt[b], 1);
    if (p < NCAND)
      cand[(size_t)b * NCAND + p] = ((unsigned long long)forder(s) << 32) |
                                    (unsigned long long)(0xFFFFFFFFu - (unsigned)i);
  }
}

// ---------- kernel B3a: partial ranks (chunked all-pairs, many CUs) ----------
__global__ __launch_bounds__(1024) void k_rankp(const unsigned long long* __restrict__ cand,
                                                int* __restrict__ rankA) {
  const int b = blockIdx.y;
  const int sc = blockIdx.x >> 3, jc = blockIdx.x & 7;
  __shared__ __align__(16) unsigned long long tile[1024];
  const unsigned long long* src = cand + (size_t)b * NCAND;
  tile[threadIdx.x] = src[jc * 1024 + threadIdx.x];
  __syncthreads();
  unsigned long long my = src[sc * 1024 + threadIdx.x];
  int r = 0;
  const ulonglong2* t2 = (const ulonglong2*)tile;
  #pragma unroll 8
  for (int t = 0; t < 512; ++t) { ulonglong2 v = t2[t]; r += (v.x > my) + (v.y > my); }
  atomicAdd(&rankA[b * NCAND + sc * 1024 + threadIdx.x], r);
}

// ---------- kernel B3b: scatter by rank ----------
__global__ void k_ranks(const unsigned long long* cand, const int* rankA,
                        int* selIdx, float* selScore) {
  int b = blockIdx.y, slot = blockIdx.x * 256 + threadIdx.x;
  unsigned long long my = cand[(size_t)b * NCAND + slot];
  int r = rankA[b * NCAND + slot];
  if (r < PRE) {
    selIdx[(size_t)b * PRE + r]   = (int)(0xFFFFFFFFu - (unsigned)(my & 0xFFFFFFFFull));
    selScore[(size_t)b * PRE + r] = funorder((unsigned)(my >> 32));
  }
}

// ---------- kernel C: decode the selected 6000 boxes per image ----------
__global__ void k_decode(Ptrs P, const float* im_info, const int* selIdx, float* boxes) {
  int r = blockIdx.x * blockDim.x + threadIdx.x;
  int b = blockIdx.y;
  if (r >= PRE) return;
  float wlim = __fsub_rn(im_info[b * 3 + 1], 1.0f);
  float hlim = __fsub_rn(im_info[b * 3 + 0], 1.0f);
  int gi = selIdx[(size_t)b * PRE + r];
  float x1, y1, x2, y2; bool valid;
  decode_one(P, b, gi, wlim, hlim, x1, y1, x2, y2, valid);
  float* o = boxes + ((size_t)b * PRE + r) * 4;
  o[0] = x1; o[1] = y1; o[2] = x2; o[3] = y2;
}

// ---------- kernel D: IoU suppression bitmasks (zero-filled lower triangle) ----------
__global__ void k_mask(const float* boxes, unsigned long long* mask) {
  int cb = blockIdx.x, rb = blockIdx.y, b = blockIdx.z;
  int t = threadIdx.x;  // 64 threads
  __shared__ float cx1[64], cy1[64], cx2[64], cy2[64], car[64];
  int j0 = cb * 64;
  int jn = min(64, PRE - j0);
  if (cb >= rb && t < jn) {
    const float* bj = boxes + ((size_t)b * PRE + j0 + t) * 4;
    float a1 = bj[0], b1 = bj[1], a2 = bj[2], b2 = bj[3];
    cx1[t] = a1; cy1[t] = b1; cx2[t] = a2; cy2[t] = b2;
    car[t] = __fmul_rn(__fadd_rn(__fsub_rn(a2, a1), 1.0f),
                       __fadd_rn(__fsub_rn(b2, b1), 1.0f));
  }
  __syncthreads();
  int i = rb * 64 + t;
  if (i >= PRE) return;
  unsigned long long bits = 0;
  if (cb >= rb) {
    const float* bi = boxes + ((size_t)b * PRE + i) * 4;
    float x1 = bi[0], y1 = bi[1], x2 = bi[2], y2 = bi[3];
    float ai = __fmul_rn(__fadd_rn(__fsub_rn(x2, x1), 1.0f),
                         __fadd_rn(__fsub_rn(y2, y1), 1.0f));
    for (int jj = 0; jj < jn; ++jj) {
      int j = j0 + jj;
      if (j <= i) continue;
      float xx1 = fmaxf(x1, cx1[jj]);
      float yy1 = fmaxf(y1, cy1[jj]);
      float xx2 = fminf(x2, cx2[jj]);
      float yy2 = fminf(y2, cy2[jj]);
      float ww = fmaxf(__fadd_rn(__fsub_rn(xx2, xx1), 1.0f), 0.0f);
      float hh = fmaxf(__fadd_rn(__fsub_rn(yy2, yy1), 1.0f), 0.0f);
      float inter = __fmul_rn(ww, hh);
      float uni = __fsub_rn(__fadd_rn(ai, car[jj]), inter);
      float iou = __fdiv_rn(inter, uni);
      if (iou > 0.7f) bits |= (1ull << jj);
    }
  }
  mask[((size_t)b * PREP + i) * MWORDS + cb] = bits;
}

// ---------- kernel E: greedy scan — SALU serial chain + 8-wave phase2 ----------
// Phase 1 insight: within a 64-row block, bit kk of `state` is frozen once row
// kk is processed (diag words only carry bits > own index), so alive = ~state
// and the chain is 3 SALU ops/row (bitcmp/cselect/or) once state is scalar
// (readfirstlane) and d comes from readlane (SGPR). Phase 2: 4 row-groups x
// 94 columns on 8 waves, row-major LDS tile (conflict-free), atomicOr once.
__global__ __launch_bounds__(512, 1) void k_scan(const unsigned long long* __restrict__ mask,
                                                 unsigned long long* __restrict__ rem) {
  const int b = blockIdx.x, tid = threadIdx.x;
  const int w = tid >> 6, l = tid & 63;
  const unsigned long long* m = mask + (size_t)b * PREP * MWORDS;

  __shared__ unsigned long long s_tile[2][64 * MWORDS];  // 2 x 47KB
  __shared__ unsigned long long s_rem[MWORDS];
  __shared__ unsigned long long s_alive;

  for (int i = tid; i < MWORDS; i += 512) s_rem[i] = 0ull;

  // DMA tile 0 into buffer 0 (slab of 64 rows = 48128 B = 47 chunks of 1KB)
  {
    const char* src = (const char*)m;
    char* dst = (char*)&s_tile[0][0];
    for (int c = w; c < 47; c += 8) {
      __builtin_amdgcn_global_load_lds(
          (const GLOBAL_AS unsigned int*)(src + c * 1024 + l * 16),
          (LDS_AS unsigned int*)(dst + c * 1024), 16, 0, 0);
    }
  }
  __syncthreads();

  const int j  = tid & 127;      // column word (active if < MWORDS)
  const int sp = tid >> 7;       // row-group of 16 rows
  const bool active = j < MWORDS;

  int cur = 0;
  for (int rb = 0; rb < MWORDS; ++rb) {
    // prefetch next tile into the other buffer (state-independent)
    if (rb + 1 < MWORDS) {
      const char* src = (const char*)(m + (size_t)(rb + 1) * 64 * MWORDS);
      char* dst = (char*)&s_tile[cur ^ 1][0];
      for (int c = w; c < 47; c += 8) {
        __builtin_amdgcn_global_load_lds(
            (const GLOBAL_AS unsigned int*)(src + c * 1024 + l * 16),
            (LDS_AS unsigned int*)(dst + c * 1024), 16, 0, 0);
      }
    }

    if (tid < 64) {                // phase 1: serial aliveness, SALU chain
      unsigned long long diag = s_tile[cur][tid * MWORDS + rb];
      unsigned vdlo = (unsigned)diag, vdhi = (unsigned)(diag >> 32);
      unsigned long long s0 = s_rem[rb];
      unsigned slo = __builtin_amdgcn_readfirstlane((unsigned)s0);
      unsigned shi = __builtin_amdgcn_readfirstlane((unsigned)(s0 >> 32));
      unsigned long long st = ((unsigned long long)shi << 32) | slo;
      #pragma unroll
      for (int kk = 0; kk < 64; ++kk) {
        unsigned dlo = __builtin_amdgcn_readlane(vdlo, kk);
        unsigned dhi = __builtin_amdgcn_readlane(vdhi, kk);
        unsigned long long d = ((unsigned long long)dhi << 32) | dlo;
        st |= ((st >> kk) & 1ull) ? 0ull : d;   // 3 SALU: bitcmp/cselect/or
      }
      if (tid == 0) { s_rem[rb] = st; s_alive = ~st; }
    }
    __syncthreads();               // publishes alive; drains prefetch DMA

    if (active && j > rb) {        // phase 2: branchless masked OR from LDS
      unsigned long long alive = s_alive;
      unsigned long long acc = 0;
      #pragma unroll
      for (int t = 0; t < 16; ++t) {
        int r = sp * 16 + t;
        unsigned long long selm = 0ull - ((alive >> r) & 1ull);
        acc |= s_tile[cur][r * MWORDS + j] & selm;
      }
      if (acc) atomicOr(&s_rem[j], acc);
    }
    __syncthreads();
    cur ^= 1;
  }

  for (int i = tid; i < 128; i += 512)
    rem[b * 128 + i] = (i < MWORDS) ? s_rem[i] : 0ull;
}

// ---------- post-NMS keys ----------
__device__ __forceinline__ unsigned long long post_key(const float* selScore,
                                                       const unsigned long long* rw,
                                                       int b, int i) {
  if (i >= PRE) return 0ull;
  bool sup = (rw[i >> 6] >> (i & 63)) & 1ull;
  float s = sup ? NEGF : selScore[(size_t)b * PRE + i];
  unsigned tiev = 0xFFFFFFFFu - (unsigned)(b * 8192 + i);
  return ((unsigned long long)forder(s) << 32) | (unsigned long long)tiev;
}

// ---------- kernel F: per-image post-NMS top-1000, chunked partial ranks ----------
__global__ __launch_bounds__(1024) void k_postp(const float* __restrict__ selScore,
                                                const unsigned long long* __restrict__ rem,
                                                int* __restrict__ rankB) {
  const int b = blockIdx.y;
  const int sc = blockIdx.x / 6, jc = blockIdx.x % 6;
  __shared__ __align__(16) unsigned long long tile[1024];
  const unsigned long long* rw = rem + b * 128;
  tile[threadIdx.x] = post_key(selScore, rw, b, jc * 1024 + threadIdx.x);
  __syncthreads();
  int slot = sc * 1024 + threadIdx.x;
  unsigned long long my = post_key(selScore, rw, b, slot);
  int r = 0;
  const ulonglong2* t2 = (const ulonglong2*)tile;
  #pragma unroll 8
  for (int t = 0; t < 512; ++t) { ulonglong2 v = t2[t]; r += (v.x > my) + (v.y > my); }
  if (slot < PRE) atomicAdd(&rankB[b * NPOSTS + slot], r);
}

__global__ void k_posts(const float* selScore, const unsigned long long* rem,
                        const int* rankB, unsigned long long* pk) {
  int b = blockIdx.y, slot = blockIdx.x * 256 + threadIdx.x;
  if (slot >= PRE) return;
  int r = rankB[b * NPOSTS + slot];
  if (r < POST) pk[(size_t)b * POST + r] = post_key(selScore, rem + b * 128, b, slot);
}

// ---------- kernel G: global top-1000 of the 4000, chunked partial ranks ----------
__global__ __launch_bounds__(1024) void k_finp(const unsigned long long* __restrict__ pk,
                                               int* __restrict__ rankC) {
  const int sc = blockIdx.x >> 2, jc = blockIdx.x & 3;
  __shared__ __align__(16) unsigned long long tile[1024];
  int ji = jc * 1024 + threadIdx.x;
  tile[threadIdx.x] = (ji < B_ * POST) ? pk[ji] : 0ull;
  __syncthreads();
  int slot = sc * 1024 + threadIdx.x;
  unsigned long long my = (slot < B_ * POST) ? pk[slot] : 0ull;
  int r = 0;
  const ulonglong2* t2 = (const ulonglong2*)tile;
  #pragma unroll 8
  for (int t = 0; t < 512; ++t) { ulonglong2 v = t2[t]; r += (v.x > my) + (v.y > my); }
  if (slot < B_ * POST) atomicAdd(&rankC[slot], r);
}

__global__ void k_fins(const unsigned long long* pk, const int* rankC,
                       const float* boxes, float* out) {
  int slot = blockIdx.x * 256 + threadIdx.x;
  if (slot >= B_ * POST) return;
  int r = rankC[slot];
  if (r < POST) {
    unsigned long long my = pk[slot];
    unsigned v = 0xFFFFFFFFu - (unsigned)(my & 0xFFFFFFFFull);
    int b = v >> 13, pos = v & 8191;
    float s = funorder((unsigned)(my >> 32));
    const float* bx = boxes + ((size_t)b * PRE + pos) * 4;
    out[r * 5 + 0] = (float)b;
    out[r * 5 + 1] = bx[0];
    out[r * 5 + 2] = bx[1];
    out[r * 5 + 3] = bx[2];
    out[r * 5 + 4] = bx[3];
    out[5 * POST + r] = s;
  }
}

// ---------- workspace layout (bytes, all 16-aligned) ----------
static constexpr size_t OFF_SC   = 0;                                    // B*N1 f32
static constexpr size_t OFF_SELS = OFF_SC   + (size_t)B_ * N1 * 4;       // B*PRE f32
static constexpr size_t OFF_SELI = OFF_SELS + (size_t)B_ * PRE * 4;      // B*PRE i32
static constexpr size_t OFF_BOX  = OFF_SELI + (size_t)B_ * PRE * 4;      // B*PRE*4 f32
static constexpr size_t OFF_MASK = OFF_BOX  + (size_t)B_ * PRE * 16;     // B*PREP*94 u64
static constexpr size_t OFF_REM  = OFF_MASK + (size_t)B_ * PREP * MWORDS * 8; // B*128 u64
static constexpr size_t OFF_PK   = OFF_REM  + (size_t)B_ * 128 * 8;      // B*POST u64
static constexpr size_t OFF_HIST = OFF_PK   + (size_t)B_ * POST * 8;     // B*4096 i32
static constexpr size_t OFF_CNT  = OFF_HIST + (size_t)B_ * 4096 * 4;     // B i32 (pad 16)
static constexpr size_t OFF_CUTM = OFF_CNT  + 16;                        // B*2 i32 (pad 32)
static constexpr size_t OFF_CAND = OFF_CUTM + 32;                        // B*NCAND u64
static constexpr size_t OFF_RKA  = OFF_CAND + (size_t)B_ * NCAND * 8;    // B*NCAND i32
static constexpr size_t OFF_RKB  = OFF_RKA  + (size_t)B_ * NCAND * 4;    // B*NPOSTS i32
static constexpr size_t OFF_RKC  = OFF_RKB  + (size_t)B_ * NPOSTS * 4;   // 4096 i32

extern "C" void kernel_launch(void* const* d_in, const int* in_sizes, int n_in,
                              void* d_out, int out_size, void* d_ws, size_t ws_size,
                              hipStream_t stream) {
  Ptrs P;
  bool interleaved = (n_in >= 2) && (in_sizes[1] == 2 * in_sizes[0]);
  for (int l = 0; l < 5; ++l) {
    if (interleaved) { P.cls[l] = (const float*)d_in[2 * l]; P.bbox[l] = (const float*)d_in[2 * l + 1]; }
    else             { P.cls[l] = (const float*)d_in[l];     P.bbox[l] = (const float*)d_in[5 + l]; }
  }
  const float* im_info = (const float*)d_in[10];

  char* ws = (char*)d_ws;
  float*              scores   = (float*)(ws + OFF_SC);
  float*              selScore = (float*)(ws + OFF_SELS);
  int*                selIdx   = (int*)(ws + OFF_SELI);
  float*              selBoxes = (float*)(ws + OFF_BOX);
  unsigned long long* maskBuf  = (unsigned long long*)(ws + OFF_MASK);
  unsigned long long* remBuf   = (unsigned long long*)(ws + OFF_REM);
  unsigned long long* postKeys = (unsigned long long*)(ws + OFF_PK);
  int*                histBuf  = (int*)(ws + OFF_HIST);
  int*                cntBuf   = (int*)(ws + OFF_CNT);
  int*                cutMBuf  = (int*)(ws + OFF_CUTM);
  unsigned long long* candBuf  = (unsigned long long*)(ws + OFF_CAND);
  int*                rankA    = (int*)(ws + OFF_RKA);
  int*                rankB    = (int*)(ws + OFF_RKB);
  int*                rankC    = (int*)(ws + OFF_RKC);
  float*              out      = (float*)d_out;

  k_init<<<128, 256, 0, stream>>>(histBuf, cntBuf, candBuf, rankA, rankB, rankC, maskBuf);
  k_scores<<<dim3((N1 + 255) / 256, B_), 256, 0, stream>>>(P, im_info, scores, histBuf);
  k_cut<<<B_, 1024, 0, stream>>>(histBuf, cutMBuf);
  k_compact<<<dim3((N1 + 255) / 256, B_), 256, 0, stream>>>(scores, cutMBuf, cntBuf, candBuf);
  k_rankp<<<dim3(64, B_), 1024, 0, stream>>>(candBuf, rankA);
  k_ranks<<<dim3(NCAND / 256, B_), 256, 0, stream>>>(candBuf, rankA, selIdx, selScore);
  k_decode<<<dim3((PRE + 255) / 256, B_), 256, 0, stream>>>(P, im_info, selIdx, selBoxes);
  k_mask<<<dim3(MWORDS, MWORDS, B_), 64, 0, stream>>>(selBoxes, maskBuf);
  k_scan<<<B_, 512, 0, stream>>>(maskBuf, remBuf);
  k_postp<<<dim3(36, B_), 1024, 0, stream>>>(selScore, remBuf, rankB);
  k_posts<<<dim3(NPOSTS / 256, B_), 256, 0, stream>>>(selScore, remBuf, rankB, postKeys);
  k_finp<<<16, 1024, 0, stream>>>(postKeys, rankC);
  k_fins<<<16, 256, 0, stream>>>(postKeys, rankC, selBoxes, out);
}

// Round 8
// 401.153 us; speedup vs baseline: 1.4969x; 1.4969x over previous
//
#include <hip/hip_runtime.h>
#include <stdint.h>
#include <math.h>

static constexpr int B_   = 4;
static constexpr int N1   = 255780;   // total anchors per image across 5 levels
static constexpr int PRE  = 6000;
static constexpr int PREP = 6016;     // padded rows (multiple of 64)
static constexpr int POST = 1000;
static constexpr int MWORDS = 94;     // ceil(6000/64)
static constexpr int NCAND = 8192;    // candidate capacity per image
static constexpr int NPOSTS = 6144;   // padded post-slot count
static constexpr float NEGF = -1000000000.0f;

__device__ __constant__ int c_OFF[6] = {0,192000,240000,252000,255000,255780};
__device__ __constant__ int c_H[5]   = {200,100,50,25,13};
__device__ __constant__ int c_W[5]   = {320,160,80,40,20};
__device__ __constant__ int c_S[5]   = {4,8,16,32,64};

struct Ptrs { const float* cls[5]; const float* bbox[5]; };

// ---------- helpers ----------
__device__ __forceinline__ unsigned forder(float f) {
  unsigned u = __float_as_uint(f);
  return (u & 0x80000000u) ? ~u : (u | 0x80000000u);
}
__device__ __forceinline__ float funorder(unsigned u) {
  u = (u & 0x80000000u) ? (u & 0x7FFFFFFFu) : ~u;
  return __uint_as_float(u);
}
__device__ __forceinline__ int bucket_of(float s) {
  int bk = (int)(s * 4096.0f);
  return max(0, min(4095, bk));
}

// base anchor (legacy +1 convention), double math == numpy float64, rint == np.round
__device__ __forceinline__ void anchor_for(int lvl, int a, float& ax1, float& ay1, float& ax2, float& ay2) {
  int st = c_S[lvl];
  double size = (double)st * (double)st;
  double c = 0.5 * (double)(st - 1);
  double r = (a == 0) ? 0.5 : (a == 1) ? 1.0 : 2.0;
  double ws = rint(sqrt(size / r));
  double hs = rint(ws * r);
  double w2 = ws * 8.0, h2 = hs * 8.0;
  ax1 = (float)(c - 0.5 * (w2 - 1.0));
  ay1 = (float)(c - 0.5 * (h2 - 1.0));
  ax2 = (float)(c + 0.5 * (w2 - 1.0));
  ay2 = (float)(c + 0.5 * (h2 - 1.0));
}

// decode one anchor exactly as the reference (per-op f32 rounding, no FMA)
__device__ __forceinline__ void decode_one(const Ptrs& P, int b, int gi, float wlim, float hlim,
                                           float& x1, float& y1, float& x2, float& y2, bool& valid) {
  int lvl = (gi >= c_OFF[4]) ? 4 : (gi >= c_OFF[3]) ? 3 : (gi >= c_OFF[2]) ? 2 : (gi >= c_OFF[1]) ? 1 : 0;
  int rem = gi - c_OFF[lvl];
  int a = rem % 3;
  int pos = rem / 3;
  int W = c_W[lvl];
  int h = pos / W, w = pos - h * W;
  size_t hw = (size_t)c_H[lvl] * W;
  const float* bb = P.bbox[lvl] + ((size_t)b * 12 + 4 * a) * hw + (size_t)h * W + w;
  float d0 = bb[0], d1 = bb[hw], d2 = bb[2 * hw], d3 = bb[3 * hw];

  float ax1, ay1, ax2, ay2;
  anchor_for(lvl, a, ax1, ay1, ax2, ay2);
  int st = c_S[lvl];
  float sx = (float)(w * st), sy = (float)(h * st);
  ax1 += sx; ax2 += sx; ay1 += sy; ay2 += sy;   // exact integers

  float aw  = __fadd_rn(__fsub_rn(ax2, ax1), 1.0f);
  float ah  = __fadd_rn(__fsub_rn(ay2, ay1), 1.0f);
  float acx = __fadd_rn(ax1, __fmul_rn(0.5f, __fsub_rn(aw, 1.0f)));
  float acy = __fadd_rn(ay1, __fmul_rn(0.5f, __fsub_rn(ah, 1.0f)));
  float ew  = (float)exp((double)d2);
  float eh  = (float)exp((double)d3);
  float pcx = __fadd_rn(__fmul_rn(d0, aw), acx);
  float pcy = __fadd_rn(__fmul_rn(d1, ah), acy);
  float pw  = __fmul_rn(ew, aw);
  float ph  = __fmul_rn(eh, ah);
  float hwf = __fmul_rn(0.5f, __fsub_rn(pw, 1.0f));
  float hhf = __fmul_rn(0.5f, __fsub_rn(ph, 1.0f));
  x1 = __fsub_rn(pcx, hwf);
  x2 = __fadd_rn(pcx, hwf);
  y1 = __fsub_rn(pcy, hhf);
  y2 = __fadd_rn(pcy, hhf);
  x1 = fminf(fmaxf(x1, 0.0f), wlim);
  x2 = fminf(fmaxf(x2, 0.0f), wlim);
  y1 = fminf(fmaxf(y1, 0.0f), hlim);
  y2 = fminf(fmaxf(y2, 0.0f), hlim);
  valid = (__fadd_rn(__fsub_rn(x2, x1), 1.0f) >= 0.0f) &&
          (__fadd_rn(__fsub_rn(y2, y1), 1.0f) >= 0.0f);
}

// ---------- kernel 0: zero hist/cnt/cand/ranks + mask padding rows ----------
__global__ void k_init(int* hist, int* cnt, unsigned long long* cand,
                       int* rankA, int* rankB, int* rankC, unsigned long long* mask) {
  int i = blockIdx.x * blockDim.x + threadIdx.x;
  int n = blockDim.x * gridDim.x;
  for (int k = i; k < B_ * 4096; k += n) hist[k] = 0;
  for (int k = i; k < B_; k += n) cnt[k] = 0;
  for (int k = i; k < B_ * NCAND; k += n) cand[k] = 0ull;
  for (int k = i; k < B_ * NCAND; k += n) rankA[k] = 0;
  for (int k = i; k < B_ * NPOSTS; k += n) rankB[k] = 0;
  for (int k = i; k < 4096; k += n) rankC[k] = 0;
  // zero padding rows PRE..PREP-1 of each image
  int padw = (PREP - PRE) * MWORDS;          // 16*94
  for (int k = i; k < B_ * padw; k += n) {
    int bb = k / padw, r = k % padw;
    mask[((size_t)bb * PREP + PRE) * MWORDS + r] = 0ull;
  }
}

// ---------- kernel A: masked scores + global histogram ----------
__global__ void k_scores(Ptrs P, const float* im_info, float* scores, int* hist) {
  int i = blockIdx.x * blockDim.x + threadIdx.x;
  int b = blockIdx.y;
  if (i >= N1) return;
  float wlim = __fsub_rn(im_info[b * 3 + 1], 1.0f);
  float hlim = __fsub_rn(im_info[b * 3 + 0], 1.0f);
  float x1, y1, x2, y2; bool valid;
  decode_one(P, b, i, wlim, hlim, x1, y1, x2, y2, valid);

  int lvl = (i >= c_OFF[4]) ? 4 : (i >= c_OFF[3]) ? 3 : (i >= c_OFF[2]) ? 2 : (i >= c_OFF[1]) ? 1 : 0;
  int rem = i - c_OFF[lvl];
  int a = rem % 3;
  int pos = rem / 3;
  int W = c_W[lvl];
  int h = pos / W, w = pos - h * W;
  size_t hw = (size_t)c_H[lvl] * W;
  float s = P.cls[lvl][((size_t)b * 6 + 3 + a) * hw + (size_t)h * W + w];
  float sv = valid ? s : NEGF;
  scores[(size_t)b * N1 + i] = sv;
  atomicAdd(&hist[b * 4096 + bucket_of(sv)], 1);
}

// ---------- kernel B1: cutoff bin per image (parallel suffix-sum) ----------
__global__ __launch_bounds__(1024) void k_cut(const int* hist, int* cutM) {
  int b = blockIdx.x, t = threadIdx.x;
  __shared__ int h[4096];
  __shared__ int ts[1024];
  __shared__ int s_cut, s_M;
  for (int i = t; i < 4096; i += 1024) h[i] = hist[b * 4096 + i];
  if (t == 0) { s_cut = -1; s_M = 0; }
  __syncthreads();
  int a0 = h[4 * t], a1 = h[4 * t + 1], a2 = h[4 * t + 2], a3 = h[4 * t + 3];
  ts[t] = a0 + a1 + a2 + a3;
  __syncthreads();
  for (int off = 1; off < 1024; off <<= 1) {
    int v = ts[t] + ((t + off < 1024) ? ts[t + off] : 0);
    __syncthreads();
    ts[t] = v;
    __syncthreads();
  }
  int tail = (t + 1 < 1024) ? ts[t + 1] : 0;
  int s3 = a3 + tail, s2 = a2 + s3, s1 = a1 + s2, s0 = a0 + s1;
  int best = -1, Mv = 0;
  if      (s3 >= PRE) { best = 4 * t + 3; Mv = s3; }
  else if (s2 >= PRE) { best = 4 * t + 2; Mv = s2; }
  else if (s1 >= PRE) { best = 4 * t + 1; Mv = s1; }
  else if (s0 >= PRE) { best = 4 * t;     Mv = s0; }
  if (best >= 0) atomicMax(&s_cut, best);
  __syncthreads();
  if (s_cut == -1) { if (t == 0) { cutM[b * 2] = 0; cutM[b * 2 + 1] = ts[0]; } return; }
  if (best == s_cut) { cutM[b * 2] = best; cutM[b * 2 + 1] = Mv; }
}

// ---------- kernel B2: compact candidate keys (unordered) ----------
__global__ void k_compact(const float* scores, const int* cutM, int* cnt,
                          unsigned long long* cand) {
  int i = blockIdx.x * blockDim.x + threadIdx.x;
  int b = blockIdx.y;
  if (i >= N1) return;
  float s = scores[(size_t)b * N1 + i];
  if (bucket_of(s) >= cutM[b * 2]) {
    int p = atomicAdd(&cnt[b], 1);
    if (p < NCAND)
      cand[(size_t)b * NCAND + p] = ((unsigned long long)forder(s) << 32) |
                                    (unsigned long long)(0xFFFFFFFFu - (unsigned)i);
  }
}

// ---------- kernel B3a: partial ranks (chunked all-pairs, many CUs) ----------
__global__ __launch_bounds__(1024) void k_rankp(const unsigned long long* __restrict__ cand,
                                                int* __restrict__ rankA) {
  const int b = blockIdx.y;
  const int sc = blockIdx.x >> 3, jc = blockIdx.x & 7;
  __shared__ __align__(16) unsigned long long tile[1024];
  const unsigned long long* src = cand + (size_t)b * NCAND;
  tile[threadIdx.x] = src[jc * 1024 + threadIdx.x];
  __syncthreads();
  unsigned long long my = src[sc * 1024 + threadIdx.x];
  int r = 0;
  const ulonglong2* t2 = (const ulonglong2*)tile;
  #pragma unroll 8
  for (int t = 0; t < 512; ++t) { ulonglong2 v = t2[t]; r += (v.x > my) + (v.y > my); }
  atomicAdd(&rankA[b * NCAND + sc * 1024 + threadIdx.x], r);
}

// ---------- kernel B3b+C fused: scatter by rank + decode boxes ----------
__global__ void k_rankdec(Ptrs P, const float* im_info,
                          const unsigned long long* cand, const int* rankA,
                          float* selScore, float* boxes) {
  int b = blockIdx.y, slot = blockIdx.x * 256 + threadIdx.x;
  unsigned long long my = cand[(size_t)b * NCAND + slot];
  int r = rankA[b * NCAND + slot];
  if (r < PRE) {
    int gi = (int)(0xFFFFFFFFu - (unsigned)(my & 0xFFFFFFFFull));
    selScore[(size_t)b * PRE + r] = funorder((unsigned)(my >> 32));
    float wlim = __fsub_rn(im_info[b * 3 + 1], 1.0f);
    float hlim = __fsub_rn(im_info[b * 3 + 0], 1.0f);
    float x1, y1, x2, y2; bool valid;
    decode_one(P, b, gi, wlim, hlim, x1, y1, x2, y2, valid);
    float* o = boxes + ((size_t)b * PRE + r) * 4;
    o[0] = x1; o[1] = y1; o[2] = x2; o[3] = y2;
  }
}

// ---------- kernel D: IoU suppression bitmasks (zero-filled lower triangle) ----------
__global__ void k_mask(const float* boxes, unsigned long long* mask) {
  int cb = blockIdx.x, rb = blockIdx.y, b = blockIdx.z;
  int t = threadIdx.x;  // 64 threads
  __shared__ float cx1[64], cy1[64], cx2[64], cy2[64], car[64];
  int j0 = cb * 64;
  int jn = min(64, PRE - j0);
  if (cb >= rb && t < jn) {
    const float* bj = boxes + ((size_t)b * PRE + j0 + t) * 4;
    float a1 = bj[0], b1 = bj[1], a2 = bj[2], b2 = bj[3];
    cx1[t] = a1; cy1[t] = b1; cx2[t] = a2; cy2[t] = b2;
    car[t] = __fmul_rn(__fadd_rn(__fsub_rn(a2, a1), 1.0f),
                       __fadd_rn(__fsub_rn(b2, b1), 1.0f));
  }
  __syncthreads();
  int i = rb * 64 + t;
  if (i >= PRE) return;
  unsigned long long bits = 0;
  if (cb >= rb) {
    const float* bi = boxes + ((size_t)b * PRE + i) * 4;
    float x1 = bi[0], y1 = bi[1], x2 = bi[2], y2 = bi[3];
    float ai = __fmul_rn(__fadd_rn(__fsub_rn(x2, x1), 1.0f),
                         __fadd_rn(__fsub_rn(y2, y1), 1.0f));
    for (int jj = 0; jj < jn; ++jj) {
      int j = j0 + jj;
      if (j <= i) continue;
      float xx1 = fmaxf(x1, cx1[jj]);
      float yy1 = fmaxf(y1, cy1[jj]);
      float xx2 = fminf(x2, cx2[jj]);
      float yy2 = fminf(y2, cy2[jj]);
      float ww = fmaxf(__fadd_rn(__fsub_rn(xx2, xx1), 1.0f), 0.0f);
      float hh = fmaxf(__fadd_rn(__fsub_rn(yy2, yy1), 1.0f), 0.0f);
      float inter = __fmul_rn(ww, hh);
      float uni = __fsub_rn(__fadd_rn(ai, car[jj]), inter);
      float iou = __fdiv_rn(inter, uni);
      if (iou > 0.7f) bits |= (1ull << jj);
    }
  }
  mask[((size_t)b * PREP + i) * MWORDS + cb] = bits;
}

// ---------- kernel E: greedy scan — lazy columns + provable early stop ----------
// Word j of the running suppression is computed just-in-time at iteration j:
// OR of m[r][j] over currently-alive rows r < 64j (512 threads, L2-cached).
// Survivors appear in descending score order, so the post-NMS top-1000 is the
// FIRST 1000 survivors: once cum-popcount(alive) >= POST after block S, all
// later rows are outside the output whether alive or not -> mark suppressed
// (s_rem prefilled ~0) and stop. Phase B chain = R7's verified logic.
__global__ __launch_bounds__(512, 1) void k_scan(const unsigned long long* __restrict__ mask,
                                                 unsigned long long* __restrict__ rem) {
  const int b = blockIdx.x, tid = threadIdx.x;
  const unsigned long long* m = mask + (size_t)b * PREP * MWORDS;

  __shared__ unsigned long long s_alive[MWORDS];
  __shared__ unsigned long long s_rem[MWORDS];
  __shared__ unsigned long long s_word;
  __shared__ int s_count, s_stop;

  for (int i = tid; i < MWORDS; i += 512) { s_alive[i] = 0ull; s_rem[i] = ~0ull; }
  if (tid == 0) { s_word = 0ull; s_count = 0; s_stop = 0; }
  __syncthreads();

  for (int j = 0; j < MWORDS; ++j) {
    // phase A: lazy word j = OR over alive rows r<64j of m[r][j]
    unsigned long long acc = 0;
    for (int r = tid; r < j * 64; r += 512) {
      if ((s_alive[r >> 6] >> (r & 63)) & 1ull)
        acc |= m[(size_t)r * MWORDS + j];
    }
    #pragma unroll
    for (int off = 32; off > 0; off >>= 1) acc |= __shfl_xor(acc, off, 64);
    if ((tid & 63) == 0 && acc) atomicOr(&s_word, acc);
    __syncthreads();

    // phase B: within-block serial chain on wave 0 (SALU, verified in R7)
    if (tid < 64) {
      unsigned long long diag = m[(size_t)(j * 64 + tid) * MWORDS + j];
      unsigned vdlo = (unsigned)diag, vdhi = (unsigned)(diag >> 32);
      unsigned long long s0 = s_word;
      unsigned slo = __builtin_amdgcn_readfirstlane((unsigned)s0);
      unsigned shi = __builtin_amdgcn_readfirstlane((unsigned)(s0 >> 32));
      unsigned long long st = ((unsigned long long)shi << 32) | slo;
      #pragma unroll
      for (int kk = 0; kk < 64; ++kk) {
        unsigned dlo = __builtin_amdgcn_readlane(vdlo, kk);
        unsigned dhi = __builtin_amdgcn_readlane(vdhi, kk);
        unsigned long long d = ((unsigned long long)dhi << 32) | dlo;
        st |= ((st >> kk) & 1ull) ? 0ull : d;
      }
      if (tid == 0) {
        unsigned long long vmask = (j < MWORDS - 1) ? ~0ull : ((1ull << 48) - 1ull);
        unsigned long long alive = (~st) & vmask;
        s_rem[j] = st;
        s_alive[j] = alive;
        s_word = 0ull;
        s_count += __popcll(alive);
        if (s_count >= POST) s_stop = 1;
      }
    }
    __syncthreads();
    if (s_stop) break;   // uniform; remaining words stay ~0 (= suppressed)
  }

  for (int i = tid; i < 128; i += 512)
    rem[b * 128 + i] = (i < MWORDS) ? s_rem[i] : 0ull;
}

// ---------- post-NMS keys ----------
__device__ __forceinline__ unsigned long long post_key(const float* selScore,
                                                       const unsigned long long* rw,
                                                       int b, int i) {
  if (i >= PRE) return 0ull;
  bool sup = (rw[i >> 6] >> (i & 63)) & 1ull;
  float s = sup ? NEGF : selScore[(size_t)b * PRE + i];
  unsigned tiev = 0xFFFFFFFFu - (unsigned)(b * 8192 + i);
  return ((unsigned long long)forder(s) << 32) | (unsigned long long)tiev;
}

// ---------- kernel F: per-image post-NMS top-1000, chunked partial ranks ----------
__global__ __launch_bounds__(1024) void k_postp(const float* __restrict__ selScore,
                                                const unsigned long long* __restrict__ rem,
                                                int* __restrict__ rankB) {
  const int b = blockIdx.y;
  const int sc = blockIdx.x / 6, jc = blockIdx.x % 6;
  __shared__ __align__(16) unsigned long long tile[1024];
  const unsigned long long* rw = rem + b * 128;
  tile[threadIdx.x] = post_key(selScore, rw, b, jc * 1024 + threadIdx.x);
  __syncthreads();
  int slot = sc * 1024 + threadIdx.x;
  unsigned long long my = post_key(selScore, rw, b, slot);
  int r = 0;
  const ulonglong2* t2 = (const ulonglong2*)tile;
  #pragma unroll 8
  for (int t = 0; t < 512; ++t) { ulonglong2 v = t2[t]; r += (v.x > my) + (v.y > my); }
  if (slot < PRE) atomicAdd(&rankB[b * NPOSTS + slot], r);
}

__global__ void k_posts(const float* selScore, const unsigned long long* rem,
                        const int* rankB, unsigned long long* pk) {
  int b = blockIdx.y, slot = blockIdx.x * 256 + threadIdx.x;
  if (slot >= PRE) return;
  int r = rankB[b * NPOSTS + slot];
  if (r < POST) pk[(size_t)b * POST + r] = post_key(selScore, rem + b * 128, b, slot);
}

// ---------- kernel G: global top-1000 of the 4000, chunked partial ranks ----------
__global__ __launch_bounds__(1024) void k_finp(const unsigned long long* __restrict__ pk,
                                               int* __restrict__ rankC) {
  const int sc = blockIdx.x >> 2, jc = blockIdx.x & 3;
  __shared__ __align__(16) unsigned long long tile[1024];
  int ji = jc * 1024 + threadIdx.x;
  tile[threadIdx.x] = (ji < B_ * POST) ? pk[ji] : 0ull;
  __syncthreads();
  int slot = sc * 1024 + threadIdx.x;
  unsigned long long my = (slot < B_ * POST) ? pk[slot] : 0ull;
  int r = 0;
  const ulonglong2* t2 = (const ulonglong2*)tile;
  #pragma unroll 8
  for (int t = 0; t < 512; ++t) { ulonglong2 v = t2[t]; r += (v.x > my) + (v.y > my); }
  if (slot < B_ * POST) atomicAdd(&rankC[slot], r);
}

__global__ void k_fins(const unsigned long long* pk, const int* rankC,
                       const float* boxes, float* out) {
  int slot = blockIdx.x * 256 + threadIdx.x;
  if (slot >= B_ * POST) return;
  int r = rankC[slot];
  if (r < POST) {
    unsigned long long my = pk[slot];
    unsigned v = 0xFFFFFFFFu - (unsigned)(my & 0xFFFFFFFFull);
    int b = v >> 13, pos = v & 8191;
    float s = funorder((unsigned)(my >> 32));
    const float* bx = boxes + ((size_t)b * PRE + pos) * 4;
    out[r * 5 + 0] = (float)b;
    out[r * 5 + 1] = bx[0];
    out[r * 5 + 2] = bx[1];
    out[r * 5 + 3] = bx[2];
    out[r * 5 + 4] = bx[3];
    out[5 * POST + r] = s;
  }
}

// ---------- workspace layout (bytes, all 16-aligned) ----------
static constexpr size_t OFF_SC   = 0;                                    // B*N1 f32
static constexpr size_t OFF_SELS = OFF_SC   + (size_t)B_ * N1 * 4;       // B*PRE f32
static constexpr size_t OFF_SELI = OFF_SELS + (size_t)B_ * PRE * 4;      // (unused)
static constexpr size_t OFF_BOX  = OFF_SELI + (size_t)B_ * PRE * 4;      // B*PRE*4 f32
static constexpr size_t OFF_MASK = OFF_BOX  + (size_t)B_ * PRE * 16;     // B*PREP*94 u64
static constexpr size_t OFF_REM  = OFF_MASK + (size_t)B_ * PREP * MWORDS * 8; // B*128 u64
static constexpr size_t OFF_PK   = OFF_REM  + (size_t)B_ * 128 * 8;      // B*POST u64
static constexpr size_t OFF_HIST = OFF_PK   + (size_t)B_ * POST * 8;     // B*4096 i32
static constexpr size_t OFF_CNT  = OFF_HIST + (size_t)B_ * 4096 * 4;     // B i32 (pad 16)
static constexpr size_t OFF_CUTM = OFF_CNT  + 16;                        // B*2 i32 (pad 32)
static constexpr size_t OFF_CAND = OFF_CUTM + 32;                        // B*NCAND u64
static constexpr size_t OFF_RKA  = OFF_CAND + (size_t)B_ * NCAND * 8;    // B*NCAND i32
static constexpr size_t OFF_RKB  = OFF_RKA  + (size_t)B_ * NCAND * 4;    // B*NPOSTS i32
static constexpr size_t OFF_RKC  = OFF_RKB  + (size_t)B_ * NPOSTS * 4;   // 4096 i32

extern "C" void kernel_launch(void* const* d_in, const int* in_sizes, int n_in,
                              void* d_out, int out_size, void* d_ws, size_t ws_size,
                              hipStream_t stream) {
  Ptrs P;
  bool interleaved = (n_in >= 2) && (in_sizes[1] == 2 * in_sizes[0]);
  for (int l = 0; l < 5; ++l) {
    if (interleaved) { P.cls[l] = (const float*)d_in[2 * l]; P.bbox[l] = (const float*)d_in[2 * l + 1]; }
    else             { P.cls[l] = (const float*)d_in[l];     P.bbox[l] = (const float*)d_in[5 + l]; }
  }
  const float* im_info = (const float*)d_in[10];

  char* ws = (char*)d_ws;
  float*              scores   = (float*)(ws + OFF_SC);
  float*              selScore = (float*)(ws + OFF_SELS);
  float*              selBoxes = (float*)(ws + OFF_BOX);
  unsigned long long* maskBuf  = (unsigned long long*)(ws + OFF_MASK);
  unsigned long long* remBuf   = (unsigned long long*)(ws + OFF_REM);
  unsigned long long* postKeys = (unsigned long long*)(ws + OFF_PK);
  int*                histBuf  = (int*)(ws + OFF_HIST);
  int*                cntBuf   = (int*)(ws + OFF_CNT);
  int*                cutMBuf  = (int*)(ws + OFF_CUTM);
  unsigned long long* candBuf  = (unsigned long long*)(ws + OFF_CAND);
  int*                rankA    = (int*)(ws + OFF_RKA);
  int*                rankB    = (int*)(ws + OFF_RKB);
  int*                rankC    = (int*)(ws + OFF_RKC);
  float*              out      = (float*)d_out;

  k_init<<<128, 256, 0, stream>>>(histBuf, cntBuf, candBuf, rankA, rankB, rankC, maskBuf);
  k_scores<<<dim3((N1 + 255) / 256, B_), 256, 0, stream>>>(P, im_info, scores, histBuf);
  k_cut<<<B_, 1024, 0, stream>>>(histBuf, cutMBuf);
  k_compact<<<dim3((N1 + 255) / 256, B_), 256, 0, stream>>>(scores, cutMBuf, cntBuf, candBuf);
  k_rankp<<<dim3(64, B_), 1024, 0, stream>>>(candBuf, rankA);
  k_rankdec<<<dim3(NCAND / 256, B_), 256, 0, stream>>>(P, im_info, candBuf, rankA, selScore, selBoxes);
  k_mask<<<dim3(MWORDS, MWORDS, B_), 64, 0, stream>>>(selBoxes, maskBuf);
  k_scan<<<B_, 512, 0, stream>>>(maskBuf, remBuf);
  k_postp<<<dim3(36, B_), 1024, 0, stream>>>(selScore, remBuf, rankB);
  k_posts<<<dim3(NPOSTS / 256, B_), 256, 0, stream>>>(selScore, remBuf, rankB, postKeys);
  k_finp<<<16, 1024, 0, stream>>>(postKeys, rankC);
  k_fins<<<16, 256, 0, stream>>>(postKeys, rankC, selBoxes, out);
}

// Round 9
// 282.885 us; speedup vs baseline: 2.1228x; 1.4181x over previous
//
#include <hip/hip_runtime.h>
#include <stdint.h>
#include <math.h>

static constexpr int B_   = 4;
static constexpr int N1   = 255780;   // total anchors per image across 5 levels
static constexpr int PRE  = 6000;
static constexpr int PREP = 6016;     // padded rows (multiple of 64)
static constexpr int POST = 1000;
static constexpr int MWORDS = 94;     // ceil(6000/64)
static constexpr int NCAND = 8192;    // candidate capacity per image
static constexpr int NPOSTS = 6144;   // padded post-slot count
static constexpr int CNTSTRIDE = 32;  // ints; 128B — one cache line per image
static constexpr float NEGF = -1000000000.0f;

__device__ __constant__ int c_OFF[6] = {0,192000,240000,252000,255000,255780};
__device__ __constant__ int c_H[5]   = {200,100,50,25,13};
__device__ __constant__ int c_W[5]   = {320,160,80,40,20};
__device__ __constant__ int c_S[5]   = {4,8,16,32,64};

struct Ptrs { const float* cls[5]; const float* bbox[5]; };

// ---------- helpers ----------
__device__ __forceinline__ unsigned forder(float f) {
  unsigned u = __float_as_uint(f);
  return (u & 0x80000000u) ? ~u : (u | 0x80000000u);
}
__device__ __forceinline__ float funorder(unsigned u) {
  u = (u & 0x80000000u) ? (u & 0x7FFFFFFFu) : ~u;
  return __uint_as_float(u);
}
__device__ __forceinline__ int bucket_of(float s) {
  int bk = (int)(s * 4096.0f);
  return max(0, min(4095, bk));
}

// base anchor (legacy +1 convention), double math == numpy float64, rint == np.round
__device__ __forceinline__ void anchor_for(int lvl, int a, float& ax1, float& ay1, float& ax2, float& ay2) {
  int st = c_S[lvl];
  double size = (double)st * (double)st;
  double c = 0.5 * (double)(st - 1);
  double r = (a == 0) ? 0.5 : (a == 1) ? 1.0 : 2.0;
  double ws = rint(sqrt(size / r));
  double hs = rint(ws * r);
  double w2 = ws * 8.0, h2 = hs * 8.0;
  ax1 = (float)(c - 0.5 * (w2 - 1.0));
  ay1 = (float)(c - 0.5 * (h2 - 1.0));
  ax2 = (float)(c + 0.5 * (w2 - 1.0));
  ay2 = (float)(c + 0.5 * (h2 - 1.0));
}

// decode one anchor exactly as the reference (per-op f32 rounding, no FMA)
__device__ __forceinline__ void decode_one(const Ptrs& P, int b, int gi, float wlim, float hlim,
                                           float& x1, float& y1, float& x2, float& y2, bool& valid) {
  int lvl = (gi >= c_OFF[4]) ? 4 : (gi >= c_OFF[3]) ? 3 : (gi >= c_OFF[2]) ? 2 : (gi >= c_OFF[1]) ? 1 : 0;
  int rem = gi - c_OFF[lvl];
  int a = rem % 3;
  int pos = rem / 3;
  int W = c_W[lvl];
  int h = pos / W, w = pos - h * W;
  size_t hw = (size_t)c_H[lvl] * W;
  const float* bb = P.bbox[lvl] + ((size_t)b * 12 + 4 * a) * hw + (size_t)h * W + w;
  float d0 = bb[0], d1 = bb[hw], d2 = bb[2 * hw], d3 = bb[3 * hw];

  float ax1, ay1, ax2, ay2;
  anchor_for(lvl, a, ax1, ay1, ax2, ay2);
  int st = c_S[lvl];
  float sx = (float)(w * st), sy = (float)(h * st);
  ax1 += sx; ax2 += sx; ay1 += sy; ay2 += sy;   // exact integers

  float aw  = __fadd_rn(__fsub_rn(ax2, ax1), 1.0f);
  float ah  = __fadd_rn(__fsub_rn(ay2, ay1), 1.0f);
  float acx = __fadd_rn(ax1, __fmul_rn(0.5f, __fsub_rn(aw, 1.0f)));
  float acy = __fadd_rn(ay1, __fmul_rn(0.5f, __fsub_rn(ah, 1.0f)));
  float ew  = (float)exp((double)d2);
  float eh  = (float)exp((double)d3);
  float pcx = __fadd_rn(__fmul_rn(d0, aw), acx);
  float pcy = __fadd_rn(__fmul_rn(d1, ah), acy);
  float pw  = __fmul_rn(ew, aw);
  float ph  = __fmul_rn(eh, ah);
  float hwf = __fmul_rn(0.5f, __fsub_rn(pw, 1.0f));
  float hhf = __fmul_rn(0.5f, __fsub_rn(ph, 1.0f));
  x1 = __fsub_rn(pcx, hwf);
  x2 = __fadd_rn(pcx, hwf);
  y1 = __fsub_rn(pcy, hhf);
  y2 = __fadd_rn(pcy, hhf);
  x1 = fminf(fmaxf(x1, 0.0f), wlim);
  x2 = fminf(fmaxf(x2, 0.0f), wlim);
  y1 = fminf(fmaxf(y1, 0.0f), hlim);
  y2 = fminf(fmaxf(y2, 0.0f), hlim);
  valid = (__fadd_rn(__fsub_rn(x2, x1), 1.0f) >= 0.0f) &&
          (__fadd_rn(__fsub_rn(y2, y1), 1.0f) >= 0.0f);
}

// ---------- kernel 0: zero hist/cnt/cand/ranks + mask padding rows ----------
__global__ void k_init(int* hist, int* cnt, unsigned long long* cand,
                       int* rankA, int* rankB, int* rankC, unsigned long long* mask) {
  int i = blockIdx.x * blockDim.x + threadIdx.x;
  int n = blockDim.x * gridDim.x;
  for (int k = i; k < B_ * 4096; k += n) hist[k] = 0;
  for (int k = i; k < B_ * CNTSTRIDE; k += n) cnt[k] = 0;
  for (int k = i; k < B_ * NCAND; k += n) cand[k] = 0ull;
  for (int k = i; k < B_ * NCAND; k += n) rankA[k] = 0;
  for (int k = i; k < B_ * NPOSTS; k += n) rankB[k] = 0;
  for (int k = i; k < 4096; k += n) rankC[k] = 0;
  // zero padding rows PRE..PREP-1 of each image
  int padw = (PREP - PRE) * MWORDS;          // 16*94
  for (int k = i; k < B_ * padw; k += n) {
    int bb = k / padw, r = k % padw;
    mask[((size_t)bb * PREP + PRE) * MWORDS + r] = 0ull;
  }
}

// ---------- kernel A: masked scores + global histogram ----------
__global__ void k_scores(Ptrs P, const float* im_info, float* scores, int* hist) {
  int i = blockIdx.x * blockDim.x + threadIdx.x;
  int b = blockIdx.y;
  if (i >= N1) return;
  float wlim = __fsub_rn(im_info[b * 3 + 1], 1.0f);
  float hlim = __fsub_rn(im_info[b * 3 + 0], 1.0f);
  float x1, y1, x2, y2; bool valid;
  decode_one(P, b, i, wlim, hlim, x1, y1, x2, y2, valid);

  int lvl = (i >= c_OFF[4]) ? 4 : (i >= c_OFF[3]) ? 3 : (i >= c_OFF[2]) ? 2 : (i >= c_OFF[1]) ? 1 : 0;
  int rem = i - c_OFF[lvl];
  int a = rem % 3;
  int pos = rem / 3;
  int W = c_W[lvl];
  int h = pos / W, w = pos - h * W;
  size_t hw = (size_t)c_H[lvl] * W;
  float s = P.cls[lvl][((size_t)b * 6 + 3 + a) * hw + (size_t)h * W + w];
  float sv = valid ? s : NEGF;
  scores[(size_t)b * N1 + i] = sv;
  atomicAdd(&hist[b * 4096 + bucket_of(sv)], 1);
}

// ---------- kernel B1: cutoff bin per image (parallel suffix-sum) ----------
__global__ __launch_bounds__(1024) void k_cut(const int* hist, int* cutM) {
  int b = blockIdx.x, t = threadIdx.x;
  __shared__ int h[4096];
  __shared__ int ts[1024];
  __shared__ int s_cut, s_M;
  for (int i = t; i < 4096; i += 1024) h[i] = hist[b * 4096 + i];
  if (t == 0) { s_cut = -1; s_M = 0; }
  __syncthreads();
  int a0 = h[4 * t], a1 = h[4 * t + 1], a2 = h[4 * t + 2], a3 = h[4 * t + 3];
  ts[t] = a0 + a1 + a2 + a3;
  __syncthreads();
  for (int off = 1; off < 1024; off <<= 1) {
    int v = ts[t] + ((t + off < 1024) ? ts[t + off] : 0);
    __syncthreads();
    ts[t] = v;
    __syncthreads();
  }
  int tail = (t + 1 < 1024) ? ts[t + 1] : 0;
  int s3 = a3 + tail, s2 = a2 + s3, s1 = a1 + s2, s0 = a0 + s1;
  int best = -1, Mv = 0;
  if      (s3 >= PRE) { best = 4 * t + 3; Mv = s3; }
  else if (s2 >= PRE) { best = 4 * t + 2; Mv = s2; }
  else if (s1 >= PRE) { best = 4 * t + 1; Mv = s1; }
  else if (s0 >= PRE) { best = 4 * t;     Mv = s0; }
  if (best >= 0) atomicMax(&s_cut, best);
  __syncthreads();
  if (s_cut == -1) { if (t == 0) { cutM[b * 2] = 0; cutM[b * 2 + 1] = ts[0]; } return; }
  if (best == s_cut) { cutM[b * 2] = best; cutM[b * 2 + 1] = Mv; }
}

// ---------- kernel B2: compact candidate keys — block-aggregated atomics ----------
// One global atomicAdd per block (not per candidate); cnt[b] padded to its own
// cache line. Slot = blockBase + waveBase + popcount(lower ballot bits);
// order is arbitrary (rank pass sorts), determinism within a launch is fine.
__global__ __launch_bounds__(256) void k_compact(const float* __restrict__ scores,
                                                 const int* __restrict__ cutM, int* cnt,
                                                 unsigned long long* __restrict__ cand) {
  const int i = blockIdx.x * blockDim.x + threadIdx.x;
  const int b = blockIdx.y;
  const int wid = threadIdx.x >> 6;
  __shared__ int wcnts[4], wbase[4];

  int cut = cutM[b * 2];
  bool isc = false;
  float s = 0.0f;
  if (i < N1) {
    s = scores[(size_t)b * N1 + i];
    isc = bucket_of(s) >= cut;
  }
  unsigned long long ball = __ballot(isc);
  if ((threadIdx.x & 63) == 0) wcnts[wid] = __popcll(ball);
  __syncthreads();
  if (threadIdx.x == 0) {
    int tot = wcnts[0] + wcnts[1] + wcnts[2] + wcnts[3];
    int base = tot ? atomicAdd(&cnt[b * CNTSTRIDE], tot) : 0;
    wbase[0] = base;
    wbase[1] = base + wcnts[0];
    wbase[2] = base + wcnts[0] + wcnts[1];
    wbase[3] = base + wcnts[0] + wcnts[1] + wcnts[2];
  }
  __syncthreads();
  if (isc) {
    unsigned long long lower = ball & ((1ull << (threadIdx.x & 63)) - 1ull);
    int p = wbase[wid] + __popcll(lower);
    if (p < NCAND)
      cand[(size_t)b * NCAND + p] = ((unsigned long long)forder(s) << 32) |
                                    (unsigned long long)(0xFFFFFFFFu - (unsigned)i);
  }
}

// ---------- kernel B3a: partial ranks (chunked all-pairs, many CUs) ----------
__global__ __launch_bounds__(1024) void k_rankp(const unsigned long long* __restrict__ cand,
                                                int* __restrict__ rankA) {
  const int b = blockIdx.y;
  const int sc = blockIdx.x >> 3, jc = blockIdx.x & 7;
  __shared__ __align__(16) unsigned long long tile[1024];
  const unsigned long long* src = cand + (size_t)b * NCAND;
  tile[threadIdx.x] = src[jc * 1024 + threadIdx.x];
  __syncthreads();
  unsigned long long my = src[sc * 1024 + threadIdx.x];
  int r = 0;
  const ulonglong2* t2 = (const ulonglong2*)tile;
  #pragma unroll 8
  for (int t = 0; t < 512; ++t) { ulonglong2 v = t2[t]; r += (v.x > my) + (v.y > my); }
  atomicAdd(&rankA[b * NCAND + sc * 1024 + threadIdx.x], r);
}

// ---------- kernel B3b+C fused: scatter by rank + decode boxes ----------
__global__ void k_rankdec(Ptrs P, const float* im_info,
                          const unsigned long long* cand, const int* rankA,
                          float* selScore, float* boxes) {
  int b = blockIdx.y, slot = blockIdx.x * 256 + threadIdx.x;
  unsigned long long my = cand[(size_t)b * NCAND + slot];
  int r = rankA[b * NCAND + slot];
  if (r < PRE) {
    int gi = (int)(0xFFFFFFFFu - (unsigned)(my & 0xFFFFFFFFull));
    selScore[(size_t)b * PRE + r] = funorder((unsigned)(my >> 32));
    float wlim = __fsub_rn(im_info[b * 3 + 1], 1.0f);
    float hlim = __fsub_rn(im_info[b * 3 + 0], 1.0f);
    float x1, y1, x2, y2; bool valid;
    decode_one(P, b, gi, wlim, hlim, x1, y1, x2, y2, valid);
    float* o = boxes + ((size_t)b * PRE + r) * 4;
    o[0] = x1; o[1] = y1; o[2] = x2; o[3] = y2;
  }
}

// ---------- kernel D: IoU suppression bitmasks (zero-filled lower triangle) ----------
__global__ void k_mask(const float* boxes, unsigned long long* mask) {
  int cb = blockIdx.x, rb = blockIdx.y, b = blockIdx.z;
  int t = threadIdx.x;  // 64 threads
  __shared__ float cx1[64], cy1[64], cx2[64], cy2[64], car[64];
  int j0 = cb * 64;
  int jn = min(64, PRE - j0);
  if (cb >= rb && t < jn) {
    const float* bj = boxes + ((size_t)b * PRE + j0 + t) * 4;
    float a1 = bj[0], b1 = bj[1], a2 = bj[2], b2 = bj[3];
    cx1[t] = a1; cy1[t] = b1; cx2[t] = a2; cy2[t] = b2;
    car[t] = __fmul_rn(__fadd_rn(__fsub_rn(a2, a1), 1.0f),
                       __fadd_rn(__fsub_rn(b2, b1), 1.0f));
  }
  __syncthreads();
  int i = rb * 64 + t;
  if (i >= PRE) return;
  unsigned long long bits = 0;
  if (cb >= rb) {
    const float* bi = boxes + ((size_t)b * PRE + i) * 4;
    float x1 = bi[0], y1 = bi[1], x2 = bi[2], y2 = bi[3];
    float ai = __fmul_rn(__fadd_rn(__fsub_rn(x2, x1), 1.0f),
                         __fadd_rn(__fsub_rn(y2, y1), 1.0f));
    for (int jj = 0; jj < jn; ++jj) {
      int j = j0 + jj;
      if (j <= i) continue;
      float xx1 = fmaxf(x1, cx1[jj]);
      float yy1 = fmaxf(y1, cy1[jj]);
      float xx2 = fminf(x2, cx2[jj]);
      float yy2 = fminf(y2, cy2[jj]);
      float ww = fmaxf(__fadd_rn(__fsub_rn(xx2, xx1), 1.0f), 0.0f);
      float hh = fmaxf(__fadd_rn(__fsub_rn(yy2, yy1), 1.0f), 0.0f);
      float inter = __fmul_rn(ww, hh);
      float uni = __fsub_rn(__fadd_rn(ai, car[jj]), inter);
      float iou = __fdiv_rn(inter, uni);
      if (iou > 0.7f) bits |= (1ull << jj);
    }
  }
  mask[((size_t)b * PREP + i) * MWORDS + cb] = bits;
}

// ---------- kernel E: greedy scan — lazy columns + provable early stop ----------
__global__ __launch_bounds__(512, 1) void k_scan(const unsigned long long* __restrict__ mask,
                                                 unsigned long long* __restrict__ rem) {
  const int b = blockIdx.x, tid = threadIdx.x;
  const unsigned long long* m = mask + (size_t)b * PREP * MWORDS;

  __shared__ unsigned long long s_alive[MWORDS];
  __shared__ unsigned long long s_rem[MWORDS];
  __shared__ unsigned long long s_word;
  __shared__ int s_count, s_stop;

  for (int i = tid; i < MWORDS; i += 512) { s_alive[i] = 0ull; s_rem[i] = ~0ull; }
  if (tid == 0) { s_word = 0ull; s_count = 0; s_stop = 0; }
  __syncthreads();

  for (int j = 0; j < MWORDS; ++j) {
    // phase A: lazy word j = OR over alive rows r<64j of m[r][j]
    unsigned long long acc = 0;
    for (int r = tid; r < j * 64; r += 512) {
      if ((s_alive[r >> 6] >> (r & 63)) & 1ull)
        acc |= m[(size_t)r * MWORDS + j];
    }
    #pragma unroll
    for (int off = 32; off > 0; off >>= 1) acc |= __shfl_xor(acc, off, 64);
    if ((tid & 63) == 0 && acc) atomicOr(&s_word, acc);
    __syncthreads();

    // phase B: within-block serial chain on wave 0 (SALU, verified in R7)
    if (tid < 64) {
      unsigned long long diag = m[(size_t)(j * 64 + tid) * MWORDS + j];
      unsigned vdlo = (unsigned)diag, vdhi = (unsigned)(diag >> 32);
      unsigned long long s0 = s_word;
      unsigned slo = __builtin_amdgcn_readfirstlane((unsigned)s0);
      unsigned shi = __builtin_amdgcn_readfirstlane((unsigned)(s0 >> 32));
      unsigned long long st = ((unsigned long long)shi << 32) | slo;
      #pragma unroll
      for (int kk = 0; kk < 64; ++kk) {
        unsigned dlo = __builtin_amdgcn_readlane(vdlo, kk);
        unsigned dhi = __builtin_amdgcn_readlane(vdhi, kk);
        unsigned long long d = ((unsigned long long)dhi << 32) | dlo;
        st |= ((st >> kk) & 1ull) ? 0ull : d;
      }
      if (tid == 0) {
        unsigned long long vmask = (j < MWORDS - 1) ? ~0ull : ((1ull << 48) - 1ull);
        unsigned long long alive = (~st) & vmask;
        s_rem[j] = st;
        s_alive[j] = alive;
        s_word = 0ull;
        s_count += __popcll(alive);
        if (s_count >= POST) s_stop = 1;
      }
    }
    __syncthreads();
    if (s_stop) break;   // uniform; remaining words stay ~0 (= suppressed)
  }

  for (int i = tid; i < 128; i += 512)
    rem[b * 128 + i] = (i < MWORDS) ? s_rem[i] : 0ull;
}

// ---------- post-NMS keys ----------
__device__ __forceinline__ unsigned long long post_key(const float* selScore,
                                                       const unsigned long long* rw,
                                                       int b, int i) {
  if (i >= PRE) return 0ull;
  bool sup = (rw[i >> 6] >> (i & 63)) & 1ull;
  float s = sup ? NEGF : selScore[(size_t)b * PRE + i];
  unsigned tiev = 0xFFFFFFFFu - (unsigned)(b * 8192 + i);
  return ((unsigned long long)forder(s) << 32) | (unsigned long long)tiev;
}

// ---------- kernel F: per-image post-NMS top-1000, chunked partial ranks ----------
__global__ __launch_bounds__(1024) void k_postp(const float* __restrict__ selScore,
                                                const unsigned long long* __restrict__ rem,
                                                int* __restrict__ rankB) {
  const int b = blockIdx.y;
  const int sc = blockIdx.x / 6, jc = blockIdx.x % 6;
  __shared__ __align__(16) unsigned long long tile[1024];
  const unsigned long long* rw = rem + b * 128;
  tile[threadIdx.x] = post_key(selScore, rw, b, jc * 1024 + threadIdx.x);
  __syncthreads();
  int slot = sc * 1024 + threadIdx.x;
  unsigned long long my = post_key(selScore, rw, b, slot);
  int r = 0;
  const ulonglong2* t2 = (const ulonglong2*)tile;
  #pragma unroll 8
  for (int t = 0; t < 512; ++t) { ulonglong2 v = t2[t]; r += (v.x > my) + (v.y > my); }
  if (slot < PRE) atomicAdd(&rankB[b * NPOSTS + slot], r);
}

__global__ void k_posts(const float* selScore, const unsigned long long* rem,
                        const int* rankB, unsigned long long* pk) {
  int b = blockIdx.y, slot = blockIdx.x * 256 + threadIdx.x;
  if (slot >= PRE) return;
  int r = rankB[b * NPOSTS + slot];
  if (r < POST) pk[(size_t)b * POST + r] = post_key(selScore, rem + b * 128, b, slot);
}

// ---------- kernel G: global top-1000 of the 4000, chunked partial ranks ----------
__global__ __launch_bounds__(1024) void k_finp(const unsigned long long* __restrict__ pk,
                                               int* __restrict__ rankC) {
  const int sc = blockIdx.x >> 2, jc = blockIdx.x & 3;
  __shared__ __align__(16) unsigned long long tile[1024];
  int ji = jc * 1024 + threadIdx.x;
  tile[threadIdx.x] = (ji < B_ * POST) ? pk[ji] : 0ull;
  __syncthreads();
  int slot = sc * 1024 + threadIdx.x;
  unsigned long long my = (slot < B_ * POST) ? pk[slot] : 0ull;
  int r = 0;
  const ulonglong2* t2 = (const ulonglong2*)tile;
  #pragma unroll 8
  for (int t = 0; t < 512; ++t) { ulonglong2 v = t2[t]; r += (v.x > my) + (v.y > my); }
  if (slot < B_ * POST) atomicAdd(&rankC[slot], r);
}

__global__ void k_fins(const unsigned long long* pk, const int* rankC,
                       const float* boxes, float* out) {
  int slot = blockIdx.x * 256 + threadIdx.x;
  if (slot >= B_ * POST) return;
  int r = rankC[slot];
  if (r < POST) {
    unsigned long long my = pk[slot];
    unsigned v = 0xFFFFFFFFu - (unsigned)(my & 0xFFFFFFFFull);
    int b = v >> 13, pos = v & 8191;
    float s = funorder((unsigned)(my >> 32));
    const float* bx = boxes + ((size_t)b * PRE + pos) * 4;
    out[r * 5 + 0] = (float)b;
    out[r * 5 + 1] = bx[0];
    out[r * 5 + 2] = bx[1];
    out[r * 5 + 3] = bx[2];
    out[r * 5 + 4] = bx[3];
    out[5 * POST + r] = s;
  }
}

// ---------- workspace layout (bytes, all 16-aligned) ----------
static constexpr size_t OFF_SC   = 0;                                    // B*N1 f32
static constexpr size_t OFF_SELS = OFF_SC   + (size_t)B_ * N1 * 4;       // B*PRE f32
static constexpr size_t OFF_SELI = OFF_SELS + (size_t)B_ * PRE * 4;      // (unused)
static constexpr size_t OFF_BOX  = OFF_SELI + (size_t)B_ * PRE * 4;      // B*PRE*4 f32
static constexpr size_t OFF_MASK = OFF_BOX  + (size_t)B_ * PRE * 16;     // B*PREP*94 u64
static constexpr size_t OFF_REM  = OFF_MASK + (size_t)B_ * PREP * MWORDS * 8; // B*128 u64
static constexpr size_t OFF_PK   = OFF_REM  + (size_t)B_ * 128 * 8;      // B*POST u64
static constexpr size_t OFF_HIST = OFF_PK   + (size_t)B_ * POST * 8;     // B*4096 i32
static constexpr size_t OFF_CNT  = OFF_HIST + (size_t)B_ * 4096 * 4;     // B*CNTSTRIDE i32
static constexpr size_t OFF_CUTM = OFF_CNT  + (size_t)B_ * CNTSTRIDE * 4;// B*2 i32 (pad 32)
static constexpr size_t OFF_CAND = OFF_CUTM + 32;                        // B*NCAND u64
static constexpr size_t OFF_RKA  = OFF_CAND + (size_t)B_ * NCAND * 8;    // B*NCAND i32
static constexpr size_t OFF_RKB  = OFF_RKA  + (size_t)B_ * NCAND * 4;    // B*NPOSTS i32
static constexpr size_t OFF_RKC  = OFF_RKB  + (size_t)B_ * NPOSTS * 4;   // 4096 i32

extern "C" void kernel_launch(void* const* d_in, const int* in_sizes, int n_in,
                              void* d_out, int out_size, void* d_ws, size_t ws_size,
                              hipStream_t stream) {
  Ptrs P;
  bool interleaved = (n_in >= 2) && (in_sizes[1] == 2 * in_sizes[0]);
  for (int l = 0; l < 5; ++l) {
    if (interleaved) { P.cls[l] = (const float*)d_in[2 * l]; P.bbox[l] = (const float*)d_in[2 * l + 1]; }
    else             { P.cls[l] = (const float*)d_in[l];     P.bbox[l] = (const float*)d_in[5 + l]; }
  }
  const float* im_info = (const float*)d_in[10];

  char* ws = (char*)d_ws;
  float*              scores   = (float*)(ws + OFF_SC);
  float*              selScore = (float*)(ws + OFF_SELS);
  float*              selBoxes = (float*)(ws + OFF_BOX);
  unsigned long long* maskBuf  = (unsigned long long*)(ws + OFF_MASK);
  unsigned long long* remBuf   = (unsigned long long*)(ws + OFF_REM);
  unsigned long long* postKeys = (unsigned long long*)(ws + OFF_PK);
  int*                histBuf  = (int*)(ws + OFF_HIST);
  int*                cntBuf   = (int*)(ws + OFF_CNT);
  int*                cutMBuf  = (int*)(ws + OFF_CUTM);
  unsigned long long* candBuf  = (unsigned long long*)(ws + OFF_CAND);
  int*                rankA    = (int*)(ws + OFF_RKA);
  int*                rankB    = (int*)(ws + OFF_RKB);
  int*                rankC    = (int*)(ws + OFF_RKC);
  float*              out      = (float*)d_out;

  k_init<<<128, 256, 0, stream>>>(histBuf, cntBuf, candBuf, rankA, rankB, rankC, maskBuf);
  k_scores<<<dim3((N1 + 255) / 256, B_), 256, 0, stream>>>(P, im_info, scores, histBuf);
  k_cut<<<B_, 1024, 0, stream>>>(histBuf, cutMBuf);
  k_compact<<<dim3((N1 + 255) / 256, B_), 256, 0, stream>>>(scores, cutMBuf, cntBuf, candBuf);
  k_rankp<<<dim3(64, B_), 1024, 0, stream>>>(candBuf, rankA);
  k_rankdec<<<dim3(NCAND / 256, B_), 256, 0, stream>>>(P, im_info, candBuf, rankA, selScore, selBoxes);
  k_mask<<<dim3(MWORDS, MWORDS, B_), 64, 0, stream>>>(selBoxes, maskBuf);
  k_scan<<<B_, 512, 0, stream>>>(maskBuf, remBuf);
  k_postp<<<dim3(36, B_), 1024, 0, stream>>>(selScore, remBuf, rankB);
  k_posts<<<dim3(NPOSTS / 256, B_), 256, 0, stream>>>(selScore, remBuf, rankB, postKeys);
  k_finp<<<16, 1024, 0, stream>>>(postKeys, rankC);
  k_fins<<<16, 256, 0, stream>>>(postKeys, rankC, selBoxes, out);
}

// Round 10
// 216.681 us; speedup vs baseline: 2.7714x; 1.3055x over previous
//
#include <hip/hip_runtime.h>
#include <stdint.h>
#include <math.h>

static constexpr int B_   = 4;
static constexpr int N1   = 255780;   // total anchors per image across 5 levels
static constexpr int PRE  = 6000;
static constexpr int PREP = 6016;     // padded rows (multiple of 64)
static constexpr int POST = 1000;
static constexpr int MWORDS = 94;     // ceil(6000/64)
static constexpr int NCAND = 8192;    // candidate capacity per image
static constexpr int NPOSTS = 6144;   // padded post-slot count
static constexpr int NBINS = 512;     // histogram bins (uniform scores: cut-bin spill ~500)
static constexpr int CNTSTRIDE = 32;  // ints; 128B — one cache line per image
static constexpr float NEGF = -1000000000.0f;

__device__ __constant__ int c_OFF[6] = {0,192000,240000,252000,255000,255780};
__device__ __constant__ int c_H[5]   = {200,100,50,25,13};
__device__ __constant__ int c_W[5]   = {320,160,80,40,20};
__device__ __constant__ int c_S[5]   = {4,8,16,32,64};

struct Ptrs { const float* cls[5]; const float* bbox[5]; };

// ---------- helpers ----------
__device__ __forceinline__ unsigned forder(float f) {
  unsigned u = __float_as_uint(f);
  return (u & 0x80000000u) ? ~u : (u | 0x80000000u);
}
__device__ __forceinline__ float funorder(unsigned u) {
  u = (u & 0x80000000u) ? (u & 0x7FFFFFFFu) : ~u;
  return __uint_as_float(u);
}
__device__ __forceinline__ int bucket_of(float s) {
  int bk = (int)(s * (float)NBINS);
  return max(0, min(NBINS - 1, bk));
}

// score gather (no decode needed: with MIN_SIZE=0 every box is provably valid —
// x2-x1+1 = pw = exp(d2)*aw > 0 pre-clip and clamping is a monotone contraction)
__device__ __forceinline__ float score_of(const Ptrs& P, int b, int i) {
  int lvl = (i >= c_OFF[4]) ? 4 : (i >= c_OFF[3]) ? 3 : (i >= c_OFF[2]) ? 2 : (i >= c_OFF[1]) ? 1 : 0;
  int rem = i - c_OFF[lvl];
  int a = rem % 3;
  int pos = rem / 3;
  size_t hw = (size_t)c_H[lvl] * c_W[lvl];
  return P.cls[lvl][((size_t)b * 6 + 3 + a) * hw + (size_t)pos];
}

// base anchor (legacy +1 convention), double math == numpy float64, rint == np.round
__device__ __forceinline__ void anchor_for(int lvl, int a, float& ax1, float& ay1, float& ax2, float& ay2) {
  int st = c_S[lvl];
  double size = (double)st * (double)st;
  double c = 0.5 * (double)(st - 1);
  double r = (a == 0) ? 0.5 : (a == 1) ? 1.0 : 2.0;
  double ws = rint(sqrt(size / r));
  double hs = rint(ws * r);
  double w2 = ws * 8.0, h2 = hs * 8.0;
  ax1 = (float)(c - 0.5 * (w2 - 1.0));
  ay1 = (float)(c - 0.5 * (h2 - 1.0));
  ax2 = (float)(c + 0.5 * (w2 - 1.0));
  ay2 = (float)(c + 0.5 * (h2 - 1.0));
}

// decode one anchor exactly as the reference (per-op f32 rounding, no FMA)
__device__ __forceinline__ void decode_one(const Ptrs& P, int b, int gi, float wlim, float hlim,
                                           float& x1, float& y1, float& x2, float& y2) {
  int lvl = (gi >= c_OFF[4]) ? 4 : (gi >= c_OFF[3]) ? 3 : (gi >= c_OFF[2]) ? 2 : (gi >= c_OFF[1]) ? 1 : 0;
  int rem = gi - c_OFF[lvl];
  int a = rem % 3;
  int pos = rem / 3;
  int W = c_W[lvl];
  int h = pos / W, w = pos - h * W;
  size_t hw = (size_t)c_H[lvl] * W;
  const float* bb = P.bbox[lvl] + ((size_t)b * 12 + 4 * a) * hw + (size_t)h * W + w;
  float d0 = bb[0], d1 = bb[hw], d2 = bb[2 * hw], d3 = bb[3 * hw];

  float ax1, ay1, ax2, ay2;
  anchor_for(lvl, a, ax1, ay1, ax2, ay2);
  int st = c_S[lvl];
  float sx = (float)(w * st), sy = (float)(h * st);
  ax1 += sx; ax2 += sx; ay1 += sy; ay2 += sy;   // exact integers

  float aw  = __fadd_rn(__fsub_rn(ax2, ax1), 1.0f);
  float ah  = __fadd_rn(__fsub_rn(ay2, ay1), 1.0f);
  float acx = __fadd_rn(ax1, __fmul_rn(0.5f, __fsub_rn(aw, 1.0f)));
  float acy = __fadd_rn(ay1, __fmul_rn(0.5f, __fsub_rn(ah, 1.0f)));
  float ew  = (float)exp((double)d2);
  float eh  = (float)exp((double)d3);
  float pcx = __fadd_rn(__fmul_rn(d0, aw), acx);
  float pcy = __fadd_rn(__fmul_rn(d1, ah), acy);
  float pw  = __fmul_rn(ew, aw);
  float ph  = __fmul_rn(eh, ah);
  float hwf = __fmul_rn(0.5f, __fsub_rn(pw, 1.0f));
  float hhf = __fmul_rn(0.5f, __fsub_rn(ph, 1.0f));
  x1 = __fsub_rn(pcx, hwf);
  x2 = __fadd_rn(pcx, hwf);
  y1 = __fsub_rn(pcy, hhf);
  y2 = __fadd_rn(pcy, hhf);
  x1 = fminf(fmaxf(x1, 0.0f), wlim);
  x2 = fminf(fmaxf(x2, 0.0f), wlim);
  y1 = fminf(fmaxf(y1, 0.0f), hlim);
  y2 = fminf(fmaxf(y2, 0.0f), hlim);
}

// ---------- kernel 0: zero hist/cnt/cand/ranks + mask padding rows ----------
__global__ void k_init(int* hist, int* cnt, unsigned long long* cand,
                       int* rankA, int* rankB, int* rankC, unsigned long long* mask) {
  int i = blockIdx.x * blockDim.x + threadIdx.x;
  int n = blockDim.x * gridDim.x;
  for (int k = i; k < B_ * NBINS; k += n) hist[k] = 0;
  for (int k = i; k < B_ * CNTSTRIDE; k += n) cnt[k] = 0;
  for (int k = i; k < B_ * NCAND; k += n) cand[k] = 0ull;
  for (int k = i; k < B_ * NCAND; k += n) rankA[k] = 0;
  for (int k = i; k < B_ * NPOSTS; k += n) rankB[k] = 0;
  for (int k = i; k < 4096; k += n) rankC[k] = 0;
  // zero padding rows PRE..PREP-1 of every column block (transposed layout)
  int padw = (PREP - PRE);                   // 16
  for (int k = i; k < B_ * MWORDS * padw; k += n) {
    int bb = k / (MWORDS * padw), r = k % (MWORDS * padw);
    int cb = r / padw, rr = r % padw;
    mask[((size_t)bb * MWORDS + cb) * PREP + PRE + rr] = 0ull;
  }
}

// ---------- kernel A: histogram of scores (LDS-aggregated, no decode) ----------
__global__ __launch_bounds__(1024) void k_hist(Ptrs P, int* hist) {
  const int b = blockIdx.y;
  __shared__ int h[NBINS];
  for (int k = threadIdx.x; k < NBINS; k += 1024) h[k] = 0;
  __syncthreads();
  const int step = gridDim.x * 1024;
  for (int i = blockIdx.x * 1024 + threadIdx.x; i < N1; i += step)
    atomicAdd(&h[bucket_of(score_of(P, b, i))], 1);
  __syncthreads();
  for (int k = threadIdx.x; k < NBINS; k += 1024) {
    int v = h[k];
    if (v) atomicAdd(&hist[b * NBINS + k], v);
  }
}

// ---------- kernel B1: cutoff bin per image (suffix-sum over NBINS) ----------
__global__ __launch_bounds__(NBINS) void k_cut(const int* hist, int* cutM) {
  int b = blockIdx.x, t = threadIdx.x;
  __shared__ int ts[NBINS];
  int mine = hist[b * NBINS + t];
  ts[t] = mine;
  __syncthreads();
  for (int off = 1; off < NBINS; off <<= 1) {
    int v = ts[t] + ((t + off < NBINS) ? ts[t + off] : 0);
    __syncthreads();
    ts[t] = v;
    __syncthreads();
  }
  // ts[t] = count of scores in bins >= t (ts[0] = N1 >= PRE always)
  int nxt = (t + 1 < NBINS) ? ts[t + 1] : 0;
  if (ts[t] >= PRE && nxt < PRE) { cutM[b * 2] = t; cutM[b * 2 + 1] = ts[t]; }
}

// ---------- kernel B2: compact candidate keys — block-aggregated atomics ----------
__global__ __launch_bounds__(256) void k_compact(Ptrs P, const int* __restrict__ cutM, int* cnt,
                                                 unsigned long long* __restrict__ cand) {
  const int i = blockIdx.x * blockDim.x + threadIdx.x;
  const int b = blockIdx.y;
  const int wid = threadIdx.x >> 6;
  __shared__ int wcnts[4], wbase[4];

  int cut = cutM[b * 2];
  bool isc = false;
  float s = 0.0f;
  if (i < N1) {
    s = score_of(P, b, i);
    isc = bucket_of(s) >= cut;
  }
  unsigned long long ball = __ballot(isc);
  if ((threadIdx.x & 63) == 0) wcnts[wid] = __popcll(ball);
  __syncthreads();
  if (threadIdx.x == 0) {
    int tot = wcnts[0] + wcnts[1] + wcnts[2] + wcnts[3];
    int base = tot ? atomicAdd(&cnt[b * CNTSTRIDE], tot) : 0;
    wbase[0] = base;
    wbase[1] = base + wcnts[0];
    wbase[2] = base + wcnts[0] + wcnts[1];
    wbase[3] = base + wcnts[0] + wcnts[1] + wcnts[2];
  }
  __syncthreads();
  if (isc) {
    unsigned long long lower = ball & ((1ull << (threadIdx.x & 63)) - 1ull);
    int p = wbase[wid] + __popcll(lower);
    if (p < NCAND)
      cand[(size_t)b * NCAND + p] = ((unsigned long long)forder(s) << 32) |
                                    (unsigned long long)(0xFFFFFFFFu - (unsigned)i);
  }
}

// ---------- kernel B3a: partial ranks (chunked all-pairs, many CUs) ----------
__global__ __launch_bounds__(1024) void k_rankp(const unsigned long long* __restrict__ cand,
                                                int* __restrict__ rankA) {
  const int b = blockIdx.y;
  const int sc = blockIdx.x >> 3, jc = blockIdx.x & 7;
  __shared__ __align__(16) unsigned long long tile[1024];
  const unsigned long long* src = cand + (size_t)b * NCAND;
  tile[threadIdx.x] = src[jc * 1024 + threadIdx.x];
  __syncthreads();
  unsigned long long my = src[sc * 1024 + threadIdx.x];
  int r = 0;
  const ulonglong2* t2 = (const ulonglong2*)tile;
  #pragma unroll 8
  for (int t = 0; t < 512; ++t) { ulonglong2 v = t2[t]; r += (v.x > my) + (v.y > my); }
  atomicAdd(&rankA[b * NCAND + sc * 1024 + threadIdx.x], r);
}

// ---------- kernel B3b+C fused: scatter by rank + decode boxes ----------
__global__ void k_rankdec(Ptrs P, const float* im_info,
                          const unsigned long long* cand, const int* rankA,
                          float* selScore, float* boxes) {
  int b = blockIdx.y, slot = blockIdx.x * 256 + threadIdx.x;
  unsigned long long my = cand[(size_t)b * NCAND + slot];
  int r = rankA[b * NCAND + slot];
  if (r < PRE) {
    int gi = (int)(0xFFFFFFFFu - (unsigned)(my & 0xFFFFFFFFull));
    selScore[(size_t)b * PRE + r] = funorder((unsigned)(my >> 32));
    float wlim = __fsub_rn(im_info[b * 3 + 1], 1.0f);
    float hlim = __fsub_rn(im_info[b * 3 + 0], 1.0f);
    float x1, y1, x2, y2;
    decode_one(P, b, gi, wlim, hlim, x1, y1, x2, y2);
    float* o = boxes + ((size_t)b * PRE + r) * 4;
    o[0] = x1; o[1] = y1; o[2] = x2; o[3] = y2;
  }
}

// ---------- kernel D: IoU bitmasks — TRANSPOSED [cb][row], upper-tri only ----------
__global__ void k_mask(const float* boxes, unsigned long long* mask) {
  int cb = blockIdx.x, rb = blockIdx.y, b = blockIdx.z;
  if (cb < rb) return;                      // lower triangle never read by k_scan
  int t = threadIdx.x;  // 64 threads
  __shared__ float cx1[64], cy1[64], cx2[64], cy2[64], car[64];
  int j0 = cb * 64;
  int jn = min(64, PRE - j0);
  if (t < jn) {
    const float* bj = boxes + ((size_t)b * PRE + j0 + t) * 4;
    float a1 = bj[0], b1 = bj[1], a2 = bj[2], b2 = bj[3];
    cx1[t] = a1; cy1[t] = b1; cx2[t] = a2; cy2[t] = b2;
    car[t] = __fmul_rn(__fadd_rn(__fsub_rn(a2, a1), 1.0f),
                       __fadd_rn(__fsub_rn(b2, b1), 1.0f));
  }
  __syncthreads();
  int i = rb * 64 + t;
  if (i >= PRE) return;
  unsigned long long bits = 0;
  {
    const float* bi = boxes + ((size_t)b * PRE + i) * 4;
    float x1 = bi[0], y1 = bi[1], x2 = bi[2], y2 = bi[3];
    float ai = __fmul_rn(__fadd_rn(__fsub_rn(x2, x1), 1.0f),
                         __fadd_rn(__fsub_rn(y2, y1), 1.0f));
    for (int jj = 0; jj < jn; ++jj) {
      int j = j0 + jj;
      if (j <= i) continue;
      float xx1 = fmaxf(x1, cx1[jj]);
      float yy1 = fmaxf(y1, cy1[jj]);
      float xx2 = fminf(x2, cx2[jj]);
      float yy2 = fminf(y2, cy2[jj]);
      float ww = fmaxf(__fadd_rn(__fsub_rn(xx2, xx1), 1.0f), 0.0f);
      float hh = fmaxf(__fadd_rn(__fsub_rn(yy2, yy1), 1.0f), 0.0f);
      float inter = __fmul_rn(ww, hh);
      float uni = __fsub_rn(__fadd_rn(ai, car[jj]), inter);
      float iou = __fdiv_rn(inter, uni);
      if (iou > 0.7f) bits |= (1ull << jj);
    }
  }
  mask[((size_t)b * MWORDS + cb) * PREP + i] = bits;   // coalesced over i
}

// ---------- kernel E: greedy scan — lazy columns + early stop (transposed reads) ----------
__global__ __launch_bounds__(512, 1) void k_scan(const unsigned long long* __restrict__ mask,
                                                 unsigned long long* __restrict__ rem) {
  const int b = blockIdx.x, tid = threadIdx.x;
  const unsigned long long* m = mask + (size_t)b * MWORDS * PREP;

  __shared__ unsigned long long s_alive[MWORDS];
  __shared__ unsigned long long s_rem[MWORDS];
  __shared__ unsigned long long s_word;
  __shared__ int s_count, s_stop;

  for (int i = tid; i < MWORDS; i += 512) { s_alive[i] = 0ull; s_rem[i] = ~0ull; }
  if (tid == 0) { s_word = 0ull; s_count = 0; s_stop = 0; }
  __syncthreads();

  for (int j = 0; j < MWORDS; ++j) {
    const unsigned long long* mcol = m + (size_t)j * PREP;
    // phase A: lazy word j = OR over alive rows r<64j of column j (coalesced)
    unsigned long long acc = 0;
    for (int r = tid; r < j * 64; r += 512) {
      if ((s_alive[r >> 6] >> (r & 63)) & 1ull)
        acc |= mcol[r];
    }
    #pragma unroll
    for (int off = 32; off > 0; off >>= 1) acc |= __shfl_xor(acc, off, 64);
    if ((tid & 63) == 0 && acc) atomicOr(&s_word, acc);
    __syncthreads();

    // phase B: within-block serial chain on wave 0 (SALU, verified in R7)
    if (tid < 64) {
      unsigned long long diag = mcol[j * 64 + tid];
      unsigned vdlo = (unsigned)diag, vdhi = (unsigned)(diag >> 32);
      unsigned long long s0 = s_word;
      unsigned slo = __builtin_amdgcn_readfirstlane((unsigned)s0);
      unsigned shi = __builtin_amdgcn_readfirstlane((unsigned)(s0 >> 32));
      unsigned long long st = ((unsigned long long)shi << 32) | slo;
      #pragma unroll
      for (int kk = 0; kk < 64; ++kk) {
        unsigned dlo = __builtin_amdgcn_readlane(vdlo, kk);
        unsigned dhi = __builtin_amdgcn_readlane(vdhi, kk);
        unsigned long long d = ((unsigned long long)dhi << 32) | dlo;
        st |= ((st >> kk) & 1ull) ? 0ull : d;
      }
      if (tid == 0) {
        unsigned long long vmask = (j < MWORDS - 1) ? ~0ull : ((1ull << 48) - 1ull);
        unsigned long long alive = (~st) & vmask;
        s_rem[j] = st;
        s_alive[j] = alive;
        s_word = 0ull;
        s_count += __popcll(alive);
        if (s_count >= POST) s_stop = 1;
      }
    }
    __syncthreads();
    if (s_stop) break;   // uniform; remaining words stay ~0 (= suppressed)
  }

  for (int i = tid; i < 128; i += 512)
    rem[b * 128 + i] = (i < MWORDS) ? s_rem[i] : 0ull;
}

// ---------- post-NMS keys ----------
__device__ __forceinline__ unsigned long long post_key(const float* selScore,
                                                       const unsigned long long* rw,
                                                       int b, int i) {
  if (i >= PRE) return 0ull;
  bool sup = (rw[i >> 6] >> (i & 63)) & 1ull;
  float s = sup ? NEGF : selScore[(size_t)b * PRE + i];
  unsigned tiev = 0xFFFFFFFFu - (unsigned)(b * 8192 + i);
  return ((unsigned long long)forder(s) << 32) | (unsigned long long)tiev;
}

// ---------- kernel F: per-image post-NMS top-1000, chunked partial ranks ----------
__global__ __launch_bounds__(1024) void k_postp(const float* __restrict__ selScore,
                                                const unsigned long long* __restrict__ rem,
                                                int* __restrict__ rankB) {
  const int b = blockIdx.y;
  const int sc = blockIdx.x / 6, jc = blockIdx.x % 6;
  __shared__ __align__(16) unsigned long long tile[1024];
  const unsigned long long* rw = rem + b * 128;
  tile[threadIdx.x] = post_key(selScore, rw, b, jc * 1024 + threadIdx.x);
  __syncthreads();
  int slot = sc * 1024 + threadIdx.x;
  unsigned long long my = post_key(selScore, rw, b, slot);
  int r = 0;
  const ulonglong2* t2 = (const ulonglong2*)tile;
  #pragma unroll 8
  for (int t = 0; t < 512; ++t) { ulonglong2 v = t2[t]; r += (v.x > my) + (v.y > my); }
  if (slot < PRE) atomicAdd(&rankB[b * NPOSTS + slot], r);
}

__global__ void k_posts(const float* selScore, const unsigned long long* rem,
                        const int* rankB, unsigned long long* pk) {
  int b = blockIdx.y, slot = blockIdx.x * 256 + threadIdx.x;
  if (slot >= PRE) return;
  int r = rankB[b * NPOSTS + slot];
  if (r < POST) pk[(size_t)b * POST + r] = post_key(selScore, rem + b * 128, b, slot);
}

// ---------- kernel G: global top-1000 of the 4000, chunked partial ranks ----------
__global__ __launch_bounds__(1024) void k_finp(const unsigned long long* __restrict__ pk,
                                               int* __restrict__ rankC) {
  const int sc = blockIdx.x >> 2, jc = blockIdx.x & 3;
  __shared__ __align__(16) unsigned long long tile[1024];
  int ji = jc * 1024 + threadIdx.x;
  tile[threadIdx.x] = (ji < B_ * POST) ? pk[ji] : 0ull;
  __syncthreads();
  int slot = sc * 1024 + threadIdx.x;
  unsigned long long my = (slot < B_ * POST) ? pk[slot] : 0ull;
  int r = 0;
  const ulonglong2* t2 = (const ulonglong2*)tile;
  #pragma unroll 8
  for (int t = 0; t < 512; ++t) { ulonglong2 v = t2[t]; r += (v.x > my) + (v.y > my); }
  if (slot < B_ * POST) atomicAdd(&rankC[slot], r);
}

__global__ void k_fins(const unsigned long long* pk, const int* rankC,
                       const float* boxes, float* out) {
  int slot = blockIdx.x * 256 + threadIdx.x;
  if (slot >= B_ * POST) return;
  int r = rankC[slot];
  if (r < POST) {
    unsigned long long my = pk[slot];
    unsigned v = 0xFFFFFFFFu - (unsigned)(my & 0xFFFFFFFFull);
    int b = v >> 13, pos = v & 8191;
    float s = funorder((unsigned)(my >> 32));
    const float* bx = boxes + ((size_t)b * PRE + pos) * 4;
    out[r * 5 + 0] = (float)b;
    out[r * 5 + 1] = bx[0];
    out[r * 5 + 2] = bx[1];
    out[r * 5 + 3] = bx[2];
    out[r * 5 + 4] = bx[3];
    out[5 * POST + r] = s;
  }
}

// ---------- workspace layout (bytes, all 16-aligned) ----------
static constexpr size_t OFF_SELS = 0;                                    // B*PRE f32
static constexpr size_t OFF_BOX  = OFF_SELS + (size_t)B_ * PRE * 4;      // B*PRE*4 f32
static constexpr size_t OFF_MASK = OFF_BOX  + (size_t)B_ * PRE * 16;     // B*94*PREP u64
static constexpr size_t OFF_REM  = OFF_MASK + (size_t)B_ * MWORDS * PREP * 8; // B*128 u64
static constexpr size_t OFF_PK   = OFF_REM  + (size_t)B_ * 128 * 8;      // B*POST u64
static constexpr size_t OFF_HIST = OFF_PK   + (size_t)B_ * POST * 8;     // B*NBINS i32
static constexpr size_t OFF_CNT  = OFF_HIST + (size_t)B_ * NBINS * 4;    // B*CNTSTRIDE i32
static constexpr size_t OFF_CUTM = OFF_CNT  + (size_t)B_ * CNTSTRIDE * 4;// B*2 i32 (pad 32)
static constexpr size_t OFF_CAND = OFF_CUTM + 32;                        // B*NCAND u64
static constexpr size_t OFF_RKA  = OFF_CAND + (size_t)B_ * NCAND * 8;    // B*NCAND i32
static constexpr size_t OFF_RKB  = OFF_RKA  + (size_t)B_ * NCAND * 4;    // B*NPOSTS i32
static constexpr size_t OFF_RKC  = OFF_RKB  + (size_t)B_ * NPOSTS * 4;   // 4096 i32

extern "C" void kernel_launch(void* const* d_in, const int* in_sizes, int n_in,
                              void* d_out, int out_size, void* d_ws, size_t ws_size,
                              hipStream_t stream) {
  Ptrs P;
  bool interleaved = (n_in >= 2) && (in_sizes[1] == 2 * in_sizes[0]);
  for (int l = 0; l < 5; ++l) {
    if (interleaved) { P.cls[l] = (const float*)d_in[2 * l]; P.bbox[l] = (const float*)d_in[2 * l + 1]; }
    else             { P.cls[l] = (const float*)d_in[l];     P.bbox[l] = (const float*)d_in[5 + l]; }
  }
  const float* im_info = (const float*)d_in[10];

  char* ws = (char*)d_ws;
  float*              selScore = (float*)(ws + OFF_SELS);
  float*              selBoxes = (float*)(ws + OFF_BOX);
  unsigned long long* maskBuf  = (unsigned long long*)(ws + OFF_MASK);
  unsigned long long* remBuf   = (unsigned long long*)(ws + OFF_REM);
  unsigned long long* postKeys = (unsigned long long*)(ws + OFF_PK);
  int*                histBuf  = (int*)(ws + OFF_HIST);
  int*                cntBuf   = (int*)(ws + OFF_CNT);
  int*                cutMBuf  = (int*)(ws + OFF_CUTM);
  unsigned long long* candBuf  = (unsigned long long*)(ws + OFF_CAND);
  int*                rankA    = (int*)(ws + OFF_RKA);
  int*                rankB    = (int*)(ws + OFF_RKB);
  int*                rankC    = (int*)(ws + OFF_RKC);
  float*              out      = (float*)d_out;

  k_init<<<128, 256, 0, stream>>>(histBuf, cntBuf, candBuf, rankA, rankB, rankC, maskBuf);
  k_hist<<<dim3(64, B_), 1024, 0, stream>>>(P, histBuf);
  k_cut<<<B_, NBINS, 0, stream>>>(histBuf, cutMBuf);
  k_compact<<<dim3((N1 + 255) / 256, B_), 256, 0, stream>>>(P, cutMBuf, cntBuf, candBuf);
  k_rankp<<<dim3(64, B_), 1024, 0, stream>>>(candBuf, rankA);
  k_rankdec<<<dim3(NCAND / 256, B_), 256, 0, stream>>>(P, im_info, candBuf, rankA, selScore, selBoxes);
  k_mask<<<dim3(MWORDS, MWORDS, B_), 64, 0, stream>>>(selBoxes, maskBuf);
  k_scan<<<B_, 512, 0, stream>>>(maskBuf, remBuf);
  k_postp<<<dim3(36, B_), 1024, 0, stream>>>(selScore, remBuf, rankB);
  k_posts<<<dim3(NPOSTS / 256, B_), 256, 0, stream>>>(selScore, remBuf, rankB, postKeys);
  k_finp<<<16, 1024, 0, stream>>>(postKeys, rankC);
  k_fins<<<16, 256, 0, stream>>>(postKeys, rankC, selBoxes, out);
}

// Round 11
// 181.073 us; speedup vs baseline: 3.3164x; 1.1967x over previous
//
#include <hip/hip_runtime.h>
#include <stdint.h>
#include <math.h>

static constexpr int B_   = 4;
static constexpr int N1   = 255780;   // total anchors per image across 5 levels
static constexpr int PRE  = 6000;
static constexpr int PREP = 6016;     // padded rows (multiple of 64)
static constexpr int POST = 1000;
static constexpr int MWORDS = 94;     // ceil(6000/64)
static constexpr int JMAX = 40;       // precomputed mask columns (stop expected ~17-25)
static constexpr int NCAND = 8192;    // candidate capacity per image
static constexpr int NPOSTS = 6144;   // padded post-slot count
static constexpr int NBINS = 512;     // histogram bins
static constexpr int CNTSTRIDE = 32;  // ints; 128B — one cache line per image
static constexpr float NEGF = -1000000000.0f;

__device__ __constant__ int c_OFF[6] = {0,192000,240000,252000,255000,255780};
__device__ __constant__ int c_H[5]   = {200,100,50,25,13};
__device__ __constant__ int c_W[5]   = {320,160,80,40,20};
__device__ __constant__ int c_S[5]   = {4,8,16,32,64};

struct Ptrs { const float* cls[5]; const float* bbox[5]; };

// ---------- helpers ----------
__device__ __forceinline__ unsigned forder(float f) {
  unsigned u = __float_as_uint(f);
  return (u & 0x80000000u) ? ~u : (u | 0x80000000u);
}
__device__ __forceinline__ float funorder(unsigned u) {
  u = (u & 0x80000000u) ? (u & 0x7FFFFFFFu) : ~u;
  return __uint_as_float(u);
}
__device__ __forceinline__ int bucket_of(float s) {
  int bk = (int)(s * (float)NBINS);
  return max(0, min(NBINS - 1, bk));
}

// Exact division-free IoU test:  rn(inter/uni) > 0.7f  ⟺  inter ≥ m·uni,
// m = 0.7f + 2^-25 (midpoint to the next float; 0.7f mantissa is odd so the
// tie rounds UP). m(25b)×uni(24b) ≤ 49 bits → double product exact. uni > 0.
__device__ __forceinline__ bool iou_gt(float x1, float y1, float x2, float y2, float ai,
                                       float bx1, float by1, float bx2, float by2, float aj) {
  float xx1 = fmaxf(x1, bx1), yy1 = fmaxf(y1, by1);
  float xx2 = fminf(x2, bx2), yy2 = fminf(y2, by2);
  float ww = fmaxf(__fadd_rn(__fsub_rn(xx2, xx1), 1.0f), 0.0f);
  float hh = fmaxf(__fadd_rn(__fsub_rn(yy2, yy1), 1.0f), 0.0f);
  float inter = __fmul_rn(ww, hh);
  float uni = __fsub_rn(__fadd_rn(ai, aj), inter);
  return (double)inter >= ((double)0.7f + 0x1p-25) * (double)uni;
}
__device__ __forceinline__ float area_of(float ax1, float ay1, float ax2, float ay2) {
  return __fmul_rn(__fadd_rn(__fsub_rn(ax2, ax1), 1.0f),
                   __fadd_rn(__fsub_rn(ay2, ay1), 1.0f));
}

// score gather (no decode needed: with MIN_SIZE=0 every box is provably valid)
__device__ __forceinline__ float score_of(const Ptrs& P, int b, int i) {
  int lvl = (i >= c_OFF[4]) ? 4 : (i >= c_OFF[3]) ? 3 : (i >= c_OFF[2]) ? 2 : (i >= c_OFF[1]) ? 1 : 0;
  int rem = i - c_OFF[lvl];
  int a = rem % 3;
  int pos = rem / 3;
  size_t hw = (size_t)c_H[lvl] * c_W[lvl];
  return P.cls[lvl][((size_t)b * 6 + 3 + a) * hw + (size_t)pos];
}

// base anchor (legacy +1 convention), double math == numpy float64, rint == np.round
__device__ __forceinline__ void anchor_for(int lvl, int a, float& ax1, float& ay1, float& ax2, float& ay2) {
  int st = c_S[lvl];
  double size = (double)st * (double)st;
  double c = 0.5 * (double)(st - 1);
  double r = (a == 0) ? 0.5 : (a == 1) ? 1.0 : 2.0;
  double ws = rint(sqrt(size / r));
  double hs = rint(ws * r);
  double w2 = ws * 8.0, h2 = hs * 8.0;
  ax1 = (float)(c - 0.5 * (w2 - 1.0));
  ay1 = (float)(c - 0.5 * (h2 - 1.0));
  ax2 = (float)(c + 0.5 * (w2 - 1.0));
  ay2 = (float)(c + 0.5 * (h2 - 1.0));
}

// decode one anchor exactly as the reference (per-op f32 rounding, no FMA)
__device__ __forceinline__ void decode_one(const Ptrs& P, int b, int gi, float wlim, float hlim,
                                           float& x1, float& y1, float& x2, float& y2) {
  int lvl = (gi >= c_OFF[4]) ? 4 : (gi >= c_OFF[3]) ? 3 : (gi >= c_OFF[2]) ? 2 : (gi >= c_OFF[1]) ? 1 : 0;
  int rem = gi - c_OFF[lvl];
  int a = rem % 3;
  int pos = rem / 3;
  int W = c_W[lvl];
  int h = pos / W, w = pos - h * W;
  size_t hw = (size_t)c_H[lvl] * W;
  const float* bb = P.bbox[lvl] + ((size_t)b * 12 + 4 * a) * hw + (size_t)h * W + w;
  float d0 = bb[0], d1 = bb[hw], d2 = bb[2 * hw], d3 = bb[3 * hw];

  float ax1, ay1, ax2, ay2;
  anchor_for(lvl, a, ax1, ay1, ax2, ay2);
  int st = c_S[lvl];
  float sx = (float)(w * st), sy = (float)(h * st);
  ax1 += sx; ax2 += sx; ay1 += sy; ay2 += sy;   // exact integers

  float aw  = __fadd_rn(__fsub_rn(ax2, ax1), 1.0f);
  float ah  = __fadd_rn(__fsub_rn(ay2, ay1), 1.0f);
  float acx = __fadd_rn(ax1, __fmul_rn(0.5f, __fsub_rn(aw, 1.0f)));
  float acy = __fadd_rn(ay1, __fmul_rn(0.5f, __fsub_rn(ah, 1.0f)));
  float ew  = (float)exp((double)d2);
  float eh  = (float)exp((double)d3);
  float pcx = __fadd_rn(__fmul_rn(d0, aw), acx);
  float pcy = __fadd_rn(__fmul_rn(d1, ah), acy);
  float pw  = __fmul_rn(ew, aw);
  float ph  = __fmul_rn(eh, ah);
  float hwf = __fmul_rn(0.5f, __fsub_rn(pw, 1.0f));
  float hhf = __fmul_rn(0.5f, __fsub_rn(ph, 1.0f));
  x1 = __fsub_rn(pcx, hwf);
  x2 = __fadd_rn(pcx, hwf);
  y1 = __fsub_rn(pcy, hhf);
  y2 = __fadd_rn(pcy, hhf);
  x1 = fminf(fmaxf(x1, 0.0f), wlim);
  x2 = fminf(fmaxf(x2, 0.0f), wlim);
  y1 = fminf(fmaxf(y1, 0.0f), hlim);
  y2 = fminf(fmaxf(y2, 0.0f), hlim);
}

// ---------- kernel 0: zero hist/cnt/cand/ranks ----------
__global__ void k_init(int* hist, int* cnt, unsigned long long* cand,
                       int* rankA, int* rankB, int* rankC) {
  int i = blockIdx.x * blockDim.x + threadIdx.x;
  int n = blockDim.x * gridDim.x;
  for (int k = i; k < B_ * NBINS; k += n) hist[k] = 0;
  for (int k = i; k < B_ * CNTSTRIDE; k += n) cnt[k] = 0;
  for (int k = i; k < B_ * NCAND; k += n) cand[k] = 0ull;
  for (int k = i; k < B_ * NCAND; k += n) rankA[k] = 0;
  for (int k = i; k < B_ * NPOSTS; k += n) rankB[k] = 0;
  for (int k = i; k < 4096; k += n) rankC[k] = 0;
}

// ---------- kernel A: histogram of scores (LDS-aggregated, no decode) ----------
__global__ __launch_bounds__(1024) void k_hist(Ptrs P, int* hist) {
  const int b = blockIdx.y;
  __shared__ int h[NBINS];
  for (int k = threadIdx.x; k < NBINS; k += 1024) h[k] = 0;
  __syncthreads();
  const int step = gridDim.x * 1024;
  for (int i = blockIdx.x * 1024 + threadIdx.x; i < N1; i += step)
    atomicAdd(&h[bucket_of(score_of(P, b, i))], 1);
  __syncthreads();
  for (int k = threadIdx.x; k < NBINS; k += 1024) {
    int v = h[k];
    if (v) atomicAdd(&hist[b * NBINS + k], v);
  }
}

// ---------- kernel B1: cutoff bin per image (suffix-sum over NBINS) ----------
__global__ __launch_bounds__(NBINS) void k_cut(const int* hist, int* cutM) {
  int b = blockIdx.x, t = threadIdx.x;
  __shared__ int ts[NBINS];
  int mine = hist[b * NBINS + t];
  ts[t] = mine;
  __syncthreads();
  for (int off = 1; off < NBINS; off <<= 1) {
    int v = ts[t] + ((t + off < NBINS) ? ts[t + off] : 0);
    __syncthreads();
    ts[t] = v;
    __syncthreads();
  }
  int nxt = (t + 1 < NBINS) ? ts[t + 1] : 0;
  if (ts[t] >= PRE && nxt < PRE) { cutM[b * 2] = t; cutM[b * 2 + 1] = ts[t]; }
}

// ---------- kernel B2: compact candidate keys — block-aggregated atomics ----------
__global__ __launch_bounds__(256) void k_compact(Ptrs P, const int* __restrict__ cutM, int* cnt,
                                                 unsigned long long* __restrict__ cand) {
  const int i = blockIdx.x * blockDim.x + threadIdx.x;
  const int b = blockIdx.y;
  const int wid = threadIdx.x >> 6;
  __shared__ int wcnts[4], wbase[4];

  int cut = cutM[b * 2];
  bool isc = false;
  float s = 0.0f;
  if (i < N1) {
    s = score_of(P, b, i);
    isc = bucket_of(s) >= cut;
  }
  unsigned long long ball = __ballot(isc);
  if ((threadIdx.x & 63) == 0) wcnts[wid] = __popcll(ball);
  __syncthreads();
  if (threadIdx.x == 0) {
    int tot = wcnts[0] + wcnts[1] + wcnts[2] + wcnts[3];
    int base = tot ? atomicAdd(&cnt[b * CNTSTRIDE], tot) : 0;
    wbase[0] = base;
    wbase[1] = base + wcnts[0];
    wbase[2] = base + wcnts[0] + wcnts[1];
    wbase[3] = base + wcnts[0] + wcnts[1] + wcnts[2];
  }
  __syncthreads();
  if (isc) {
    unsigned long long lower = ball & ((1ull << (threadIdx.x & 63)) - 1ull);
    int p = wbase[wid] + __popcll(lower);
    if (p < NCAND)
      cand[(size_t)b * NCAND + p] = ((unsigned long long)forder(s) << 32) |
                                    (unsigned long long)(0xFFFFFFFFu - (unsigned)i);
  }
}

// ---------- kernel B3a: partial ranks (chunked all-pairs, many CUs) ----------
__global__ __launch_bounds__(1024) void k_rankp(const unsigned long long* __restrict__ cand,
                                                int* __restrict__ rankA) {
  const int b = blockIdx.y;
  const int sc = blockIdx.x >> 3, jc = blockIdx.x & 7;
  __shared__ __align__(16) unsigned long long tile[1024];
  const unsigned long long* src = cand + (size_t)b * NCAND;
  tile[threadIdx.x] = src[jc * 1024 + threadIdx.x];
  __syncthreads();
  unsigned long long my = src[sc * 1024 + threadIdx.x];
  int r = 0;
  const ulonglong2* t2 = (const ulonglong2*)tile;
  #pragma unroll 8
  for (int t = 0; t < 512; ++t) { ulonglong2 v = t2[t]; r += (v.x > my) + (v.y > my); }
  atomicAdd(&rankA[b * NCAND + sc * 1024 + threadIdx.x], r);
}

// ---------- kernel B3b+C fused: scatter by rank + decode boxes ----------
__global__ void k_rankdec(Ptrs P, const float* im_info,
                          const unsigned long long* cand, const int* rankA,
                          float* selScore, float* boxes) {
  int b = blockIdx.y, slot = blockIdx.x * 256 + threadIdx.x;
  unsigned long long my = cand[(size_t)b * NCAND + slot];
  int r = rankA[b * NCAND + slot];
  if (r < PRE) {
    int gi = (int)(0xFFFFFFFFu - (unsigned)(my & 0xFFFFFFFFull));
    selScore[(size_t)b * PRE + r] = funorder((unsigned)(my >> 32));
    float wlim = __fsub_rn(im_info[b * 3 + 1], 1.0f);
    float hlim = __fsub_rn(im_info[b * 3 + 0], 1.0f);
    float x1, y1, x2, y2;
    decode_one(P, b, gi, wlim, hlim, x1, y1, x2, y2);
    float* o = boxes + ((size_t)b * PRE + r) * 4;
    o[0] = x1; o[1] = y1; o[2] = x2; o[3] = y2;
  }
}

// ---------- kernel D: IoU bitmasks — columns cb<JMAX only, transposed [cb][row] ----------
__global__ void k_mask(const float* boxes, unsigned long long* mask) {
  int cb = blockIdx.x, rb = blockIdx.y, b = blockIdx.z;
  if (rb > cb) return;                      // lower triangle never read
  int t = threadIdx.x;  // 64 threads
  __shared__ float cx1[64], cy1[64], cx2[64], cy2[64], car[64];
  int j0 = cb * 64;
  int jn = min(64, PRE - j0);
  if (t < jn) {
    const float* bj = boxes + ((size_t)b * PRE + j0 + t) * 4;
    float a1 = bj[0], b1 = bj[1], a2 = bj[2], b2 = bj[3];
    cx1[t] = a1; cy1[t] = b1; cx2[t] = a2; cy2[t] = b2;
    car[t] = area_of(a1, b1, a2, b2);
  }
  __syncthreads();
  int i = rb * 64 + t;
  if (i >= PRE) return;
  const float* bi = boxes + ((size_t)b * PRE + i) * 4;
  float x1 = bi[0], y1 = bi[1], x2 = bi[2], y2 = bi[3];
  float ai = area_of(x1, y1, x2, y2);
  unsigned long long bits = 0;
  if (cb > rb) {
    for (int jj = 0; jj < jn; ++jj)
      if (iou_gt(x1, y1, x2, y2, ai, cx1[jj], cy1[jj], cx2[jj], cy2[jj], car[jj]))
        bits |= (1ull << jj);
  } else {                                  // diagonal block: j > i only
    for (int jj = t + 1; jj < jn; ++jj)
      if (iou_gt(x1, y1, x2, y2, ai, cx1[jj], cy1[jj], cx2[jj], cy2[jj], car[jj]))
        bits |= (1ull << jj);
  }
  mask[((size_t)b * JMAX + cb) * PREP + i] = bits;   // coalesced over i
}

// ---------- kernel E: greedy scan — lazy columns + early stop + fused-IoU fallback ----------
// Columns j < JMAX read the precomputed mask; j >= JMAX (only if the stop has
// not hit by then) compute the word/diag on the fly from LDS-resident boxes
// using the SAME iou_gt — bit-identical to the precomputed path.
__global__ __launch_bounds__(512, 1) void k_scan(const float* __restrict__ boxes,
                                                 const unsigned long long* __restrict__ mask,
                                                 unsigned long long* __restrict__ rem) {
  const int b = blockIdx.x, tid = threadIdx.x;
  const unsigned long long* m = mask + (size_t)b * JMAX * PREP;

  __shared__ float4 s_box[PRE];             // 96 KB (loaded only if fallback needed)
  __shared__ unsigned long long s_alive[MWORDS];
  __shared__ unsigned long long s_rem[MWORDS];
  __shared__ unsigned long long s_word;
  __shared__ int s_count, s_stop;

  for (int i = tid; i < MWORDS; i += 512) { s_alive[i] = 0ull; s_rem[i] = ~0ull; }
  if (tid == 0) { s_word = 0ull; s_count = 0; s_stop = 0; }
  __syncthreads();

  bool loaded = false;
  for (int j = 0; j < MWORDS; ++j) {
    if (j >= JMAX && !loaded) {             // block-uniform lazy box load
      for (int r = tid; r < PRE; r += 512)
        s_box[r] = ((const float4*)boxes)[(size_t)b * PRE + r];
      __syncthreads();
      loaded = true;
    }

    // phase A: word j = OR over alive rows r<64j
    if (j < JMAX) {
      const unsigned long long* mcol = m + (size_t)j * PREP;
      unsigned long long acc = 0;
      for (int r = tid; r < j * 64; r += 512) {
        if ((s_alive[r >> 6] >> (r & 63)) & 1ull)
          acc |= mcol[r];
      }
      #pragma unroll
      for (int off = 32; off > 0; off >>= 1) acc |= __shfl_xor(acc, off, 64);
      if ((tid & 63) == 0 && acc) atomicOr(&s_word, acc);
    } else {
      // fused: wave w handles rows ≡ w (mod 8); lane jj = column within block
      int w = tid >> 6, jj = tid & 63;
      int col = j * 64 + jj;
      bool supp = false;
      if (col < PRE) {
        float4 cb4 = s_box[col];
        float caj = area_of(cb4.x, cb4.y, cb4.z, cb4.w);
        for (int r = w; r < j * 64; r += 8) {      // r wave-uniform -> cheap skip
          if ((s_alive[r >> 6] >> (r & 63)) & 1ull) {
            float4 rb4 = s_box[r];
            supp |= iou_gt(rb4.x, rb4.y, rb4.z, rb4.w,
                           area_of(rb4.x, rb4.y, rb4.z, rb4.w),
                           cb4.x, cb4.y, cb4.z, cb4.w, caj);
          }
        }
      }
      unsigned long long word = __ballot(supp);
      if ((tid & 63) == 0 && word) atomicOr(&s_word, word);
    }
    __syncthreads();

    // phase B: within-block serial chain on wave 0 (SALU, verified R7-R10)
    if (tid < 64) {
      unsigned long long diag = 0ull;
      int row = j * 64 + tid;
      if (j < JMAX) {
        diag = m[(size_t)j * PREP + row];
      } else if (row < PRE) {
        float4 bi4 = s_box[row];
        float ai = area_of(bi4.x, bi4.y, bi4.z, bi4.w);
        int jn = min(64, PRE - j * 64);
        for (int jj = tid + 1; jj < jn; ++jj) {
          float4 bj4 = s_box[j * 64 + jj];
          if (iou_gt(bi4.x, bi4.y, bi4.z, bi4.w, ai,
                     bj4.x, bj4.y, bj4.z, bj4.w,
                     area_of(bj4.x, bj4.y, bj4.z, bj4.w)))
            diag |= (1ull << jj);
        }
      }
      unsigned vdlo = (unsigned)diag, vdhi = (unsigned)(diag >> 32);
      unsigned long long s0 = s_word;
      unsigned slo = __builtin_amdgcn_readfirstlane((unsigned)s0);
      unsigned shi = __builtin_amdgcn_readfirstlane((unsigned)(s0 >> 32));
      unsigned long long st = ((unsigned long long)shi << 32) | slo;
      #pragma unroll
      for (int kk = 0; kk < 64; ++kk) {
        unsigned dlo = __builtin_amdgcn_readlane(vdlo, kk);
        unsigned dhi = __builtin_amdgcn_readlane(vdhi, kk);
        unsigned long long d = ((unsigned long long)dhi << 32) | dlo;
        st |= ((st >> kk) & 1ull) ? 0ull : d;
      }
      if (tid == 0) {
        unsigned long long vmask = (j < MWORDS - 1) ? ~0ull : ((1ull << 48) - 1ull);
        unsigned long long alive = (~st) & vmask;
        s_rem[j] = st;
        s_alive[j] = alive;
        s_word = 0ull;
        s_count += __popcll(alive);
        if (s_count >= POST) s_stop = 1;
      }
    }
    __syncthreads();
    if (s_stop) break;   // uniform; remaining words stay ~0 (= suppressed)
  }

  for (int i = tid; i < 128; i += 512)
    rem[b * 128 + i] = (i < MWORDS) ? s_rem[i] : 0ull;
}

// ---------- post-NMS keys ----------
__device__ __forceinline__ unsigned long long post_key(const float* selScore,
                                                       const unsigned long long* rw,
                                                       int b, int i) {
  if (i >= PRE) return 0ull;
  bool sup = (rw[i >> 6] >> (i & 63)) & 1ull;
  float s = sup ? NEGF : selScore[(size_t)b * PRE + i];
  unsigned tiev = 0xFFFFFFFFu - (unsigned)(b * 8192 + i);
  return ((unsigned long long)forder(s) << 32) | (unsigned long long)tiev;
}

// ---------- kernel F: per-image post-NMS top-1000, chunked partial ranks ----------
__global__ __launch_bounds__(1024) void k_postp(const float* __restrict__ selScore,
                                                const unsigned long long* __restrict__ rem,
                                                int* __restrict__ rankB) {
  const int b = blockIdx.y;
  const int sc = blockIdx.x / 6, jc = blockIdx.x % 6;
  __shared__ __align__(16) unsigned long long tile[1024];
  const unsigned long long* rw = rem + b * 128;
  tile[threadIdx.x] = post_key(selScore, rw, b, jc * 1024 + threadIdx.x);
  __syncthreads();
  int slot = sc * 1024 + threadIdx.x;
  unsigned long long my = post_key(selScore, rw, b, slot);
  int r = 0;
  const ulonglong2* t2 = (const ulonglong2*)tile;
  #pragma unroll 8
  for (int t = 0; t < 512; ++t) { ulonglong2 v = t2[t]; r += (v.x > my) + (v.y > my); }
  if (slot < PRE) atomicAdd(&rankB[b * NPOSTS + slot], r);
}

__global__ void k_posts(const float* selScore, const unsigned long long* rem,
                        const int* rankB, unsigned long long* pk) {
  int b = blockIdx.y, slot = blockIdx.x * 256 + threadIdx.x;
  if (slot >= PRE) return;
  int r = rankB[b * NPOSTS + slot];
  if (r < POST) pk[(size_t)b * POST + r] = post_key(selScore, rem + b * 128, b, slot);
}

// ---------- kernel G: global top-1000 of the 4000, chunked partial ranks ----------
__global__ __launch_bounds__(1024) void k_finp(const unsigned long long* __restrict__ pk,
                                               int* __restrict__ rankC) {
  const int sc = blockIdx.x >> 2, jc = blockIdx.x & 3;
  __shared__ __align__(16) unsigned long long tile[1024];
  int ji = jc * 1024 + threadIdx.x;
  tile[threadIdx.x] = (ji < B_ * POST) ? pk[ji] : 0ull;
  __syncthreads();
  int slot = sc * 1024 + threadIdx.x;
  unsigned long long my = (slot < B_ * POST) ? pk[slot] : 0ull;
  int r = 0;
  const ulonglong2* t2 = (const ulonglong2*)tile;
  #pragma unroll 8
  for (int t = 0; t < 512; ++t) { ulonglong2 v = t2[t]; r += (v.x > my) + (v.y > my); }
  if (slot < B_ * POST) atomicAdd(&rankC[slot], r);
}

__global__ void k_fins(const unsigned long long* pk, const int* rankC,
                       const float* boxes, float* out) {
  int slot = blockIdx.x * 256 + threadIdx.x;
  if (slot >= B_ * POST) return;
  int r = rankC[slot];
  if (r < POST) {
    unsigned long long my = pk[slot];
    unsigned v = 0xFFFFFFFFu - (unsigned)(my & 0xFFFFFFFFull);
    int b = v >> 13, pos = v & 8191;
    float s = funorder((unsigned)(my >> 32));
    const float* bx = boxes + ((size_t)b * PRE + pos) * 4;
    out[r * 5 + 0] = (float)b;
    out[r * 5 + 1] = bx[0];
    out[r * 5 + 2] = bx[1];
    out[r * 5 + 3] = bx[2];
    out[r * 5 + 4] = bx[3];
    out[5 * POST + r] = s;
  }
}

// ---------- workspace layout (bytes, all 16-aligned) ----------
static constexpr size_t OFF_SELS = 0;                                    // B*PRE f32
static constexpr size_t OFF_BOX  = OFF_SELS + (size_t)B_ * PRE * 4;      // B*PRE*4 f32
static constexpr size_t OFF_MASK = OFF_BOX  + (size_t)B_ * PRE * 16;     // B*JMAX*PREP u64
static constexpr size_t OFF_REM  = OFF_MASK + (size_t)B_ * JMAX * PREP * 8; // B*128 u64
static constexpr size_t OFF_PK   = OFF_REM  + (size_t)B_ * 128 * 8;      // B*POST u64
static constexpr size_t OFF_HIST = OFF_PK   + (size_t)B_ * POST * 8;     // B*NBINS i32
static constexpr size_t OFF_CNT  = OFF_HIST + (size_t)B_ * NBINS * 4;    // B*CNTSTRIDE i32
static constexpr size_t OFF_CUTM = OFF_CNT  + (size_t)B_ * CNTSTRIDE * 4;// B*2 i32 (pad 32)
static constexpr size_t OFF_CAND = OFF_CUTM + 32;                        // B*NCAND u64
static constexpr size_t OFF_RKA  = OFF_CAND + (size_t)B_ * NCAND * 8;    // B*NCAND i32
static constexpr size_t OFF_RKB  = OFF_RKA  + (size_t)B_ * NCAND * 4;    // B*NPOSTS i32
static constexpr size_t OFF_RKC  = OFF_RKB  + (size_t)B_ * NPOSTS * 4;   // 4096 i32

extern "C" void kernel_launch(void* const* d_in, const int* in_sizes, int n_in,
                              void* d_out, int out_size, void* d_ws, size_t ws_size,
                              hipStream_t stream) {
  Ptrs P;
  bool interleaved = (n_in >= 2) && (in_sizes[1] == 2 * in_sizes[0]);
  for (int l = 0; l < 5; ++l) {
    if (interleaved) { P.cls[l] = (const float*)d_in[2 * l]; P.bbox[l] = (const float*)d_in[2 * l + 1]; }
    else             { P.cls[l] = (const float*)d_in[l];     P.bbox[l] = (const float*)d_in[5 + l]; }
  }
  const float* im_info = (const float*)d_in[10];

  char* ws = (char*)d_ws;
  float*              selScore = (float*)(ws + OFF_SELS);
  float*              selBoxes = (float*)(ws + OFF_BOX);
  unsigned long long* maskBuf  = (unsigned long long*)(ws + OFF_MASK);
  unsigned long long* remBuf   = (unsigned long long*)(ws + OFF_REM);
  unsigned long long* postKeys = (unsigned long long*)(ws + OFF_PK);
  int*                histBuf  = (int*)(ws + OFF_HIST);
  int*                cntBuf   = (int*)(ws + OFF_CNT);
  int*                cutMBuf  = (int*)(ws + OFF_CUTM);
  unsigned long long* candBuf  = (unsigned long long*)(ws + OFF_CAND);
  int*                rankA    = (int*)(ws + OFF_RKA);
  int*                rankB    = (int*)(ws + OFF_RKB);
  int*                rankC    = (int*)(ws + OFF_RKC);
  float*              out      = (float*)d_out;

  k_init<<<128, 256, 0, stream>>>(histBuf, cntBuf, candBuf, rankA, rankB, rankC);
  k_hist<<<dim3(64, B_), 1024, 0, stream>>>(P, histBuf);
  k_cut<<<B_, NBINS, 0, stream>>>(histBuf, cutMBuf);
  k_compact<<<dim3((N1 + 255) / 256, B_), 256, 0, stream>>>(P, cutMBuf, cntBuf, candBuf);
  k_rankp<<<dim3(64, B_), 1024, 0, stream>>>(candBuf, rankA);
  k_rankdec<<<dim3(NCAND / 256, B_), 256, 0, stream>>>(P, im_info, candBuf, rankA, selScore, selBoxes);
  k_mask<<<dim3(JMAX, JMAX, B_), 64, 0, stream>>>(selBoxes, maskBuf);
  k_scan<<<B_, 512, 0, stream>>>(selBoxes, maskBuf, remBuf);
  k_postp<<<dim3(36, B_), 1024, 0, stream>>>(selScore, remBuf, rankB);
  k_posts<<<dim3(NPOSTS / 256, B_), 256, 0, stream>>>(selScore, remBuf, rankB, postKeys);
  k_finp<<<16, 1024, 0, stream>>>(postKeys, rankC);
  k_fins<<<16, 256, 0, stream>>>(postKeys, rankC, selBoxes, out);
}